// Round 1
// baseline (53209.637 us; speedup 1.0000x reference)
//
#include <hip/hip_runtime.h>
#include <stdint.h>
#include <math.h>

// ---------------------------------------------------------------------------
// NMT seq2seq: encoder LSTM (S=1024) -> decoder LSTM + local attention (T=64)
// -> fused projection/log-softmax NLL.  All f32 inputs; internal scan in f16
// (weights/activations) with f32 accumulation and f32 cell state.
// ---------------------------------------------------------------------------

typedef _Float16 f16;
typedef _Float16 f16x2 __attribute__((ext_vector_type(2)));
typedef _Float16 f16x8 __attribute__((ext_vector_type(8)));

union V8 { f16x8 v; f16x2 p[4]; float4 f4; };

__device__ __forceinline__ float dot2f(f16x2 a, f16x2 b, float c) {
#if __has_builtin(__builtin_amdgcn_fdot2)
    return __builtin_amdgcn_fdot2(a, b, c, false);
#else
    return c + (float)a[0] * (float)b[0] + (float)a[1] * (float)b[1];
#endif
}

__device__ __forceinline__ float sigf(float x) { return 1.0f / (1.0f + __expf(-x)); }

__device__ __forceinline__ float tanh_f(float x) {
    float ax = fminf(fabsf(x), 12.0f);
    float e  = __expf(2.0f * ax);
    float r  = (e - 1.0f) / (e + 1.0f);
    return copysignf(r, x);
}

// gate-column permutation: local col n (0..2047) -> original row in (4H) space.
// n = w*32 + g*8 + u  maps to  g*512 + w*8 + u   (WG w owns hidden units w*8..w*8+7)
__device__ __forceinline__ int rowp(int n) {
    return ((n >> 3) & 3) * 512 + (n >> 5) * 8 + (n & 7);
}

// Device-wide barrier among 64 workgroups (all co-resident: 64 WGs << 256 CUs).
__device__ __forceinline__ void gbar(int* ctr, int target) {
    __syncthreads();
    if (threadIdx.x == 0) {
        __threadfence();                 // release: flush stores to coherence point
        atomicAdd(ctr, 1);
        while (__hip_atomic_load(ctr, __ATOMIC_RELAXED, __HIP_MEMORY_SCOPE_AGENT) < target)
            __builtin_amdgcn_s_sleep(2);
        __threadfence();                 // acquire: invalidate stale L1/L2
    }
    __syncthreads();
}

// ---------------------------------------------------------------------------
__global__ void zero_ws(uint32_t* p, int n) {
    int i = blockIdx.x * blockDim.x + threadIdx.x;
    int st = gridDim.x * blockDim.x;
    for (; i < n; i += st) p[i] = 0u;
}

// Convert / permute weights to f16 scan layouts.
__global__ void convert_weights(const float* __restrict__ encWhh,
                                const float* __restrict__ decWih,
                                const float* __restrict__ decWhh,
                                const float* __restrict__ ht2tan,
                                const float* __restrict__ ct2ht,
                                f16* __restrict__ Wenc, f16* __restrict__ Wdih,
                                f16* __restrict__ Wdhh, f16* __restrict__ T2l,
                                f16* __restrict__ CT2l) {
    const int NW = 2048 * 512;
    const int total = 3 * NW + 512 * 512 + 512 * 1024;
    int i = blockIdx.x * blockDim.x + threadIdx.x;
    int st = gridDim.x * blockDim.x;
    for (; i < total; i += st) {
        if (i < NW) {
            int n = i >> 9, k = i & 511;
            Wenc[i] = (f16)encWhh[rowp(n) * 512 + k];
        } else if (i < 2 * NW) {
            int j = i - NW; int n = j >> 9, k = j & 511;
            Wdih[j] = (f16)decWih[rowp(n) * 1024 + 512 + k];   // ht part of concat
        } else if (i < 3 * NW) {
            int j = i - 2 * NW; int n = j >> 9, k = j & 511;
            Wdhh[j] = (f16)decWhh[rowp(n) * 512 + k];
        } else if (i < 3 * NW + 512 * 512) {
            int j = i - 3 * NW;
            T2l[j] = (f16)ht2tan[j];
        } else {
            int j = i - 3 * NW - 512 * 512;
            CT2l[j] = (f16)ct2ht[j];
        }
    }
}

// Generic 64x64-tile f32 GEMM with gathered A rows (embedding lookup), bias,
// optional output-column permutation.  C[r][n] = emb[idx[r]] . W[perm(n)] + b.
template <typename OutT, int PERM>
__global__ __launch_bounds__(256) void gemm_gather(
    const float* __restrict__ emb, const int* __restrict__ idx,
    const float* __restrict__ W, int ldw, int koff,
    const float* __restrict__ bias, OutT* __restrict__ out) {
    __shared__ float As[16][65];
    __shared__ float Bs[16][65];
    const int tid = threadIdx.x;
    const int n0 = blockIdx.x * 64;
    const int r0 = blockIdx.y * 64;
    const int tx = tid & 15, ty = tid >> 4;
    const int lk = tid & 3,  lr = tid >> 2;
    const float* arow = emb + (size_t)idx[r0 + lr] * 512 + lk * 4;
    const int nb = n0 + lr;
    const int wr = PERM ? rowp(nb) : nb;
    const float* brow = W + (size_t)wr * ldw + koff + lk * 4;
    float acc[4][4] = {};
    for (int k0 = 0; k0 < 512; k0 += 16) {
        float4 av = *(const float4*)(arow + k0);
        float4 bv = *(const float4*)(brow + k0);
        __syncthreads();
        As[lk * 4 + 0][lr] = av.x; As[lk * 4 + 1][lr] = av.y;
        As[lk * 4 + 2][lr] = av.z; As[lk * 4 + 3][lr] = av.w;
        Bs[lk * 4 + 0][lr] = bv.x; Bs[lk * 4 + 1][lr] = bv.y;
        Bs[lk * 4 + 2][lr] = bv.z; Bs[lk * 4 + 3][lr] = bv.w;
        __syncthreads();
#pragma unroll
        for (int k = 0; k < 16; k++) {
            float a4[4], b4[4];
#pragma unroll
            for (int i = 0; i < 4; i++) a4[i] = As[k][ty * 4 + i];
#pragma unroll
            for (int j = 0; j < 4; j++) b4[j] = Bs[k][tx * 4 + j];
#pragma unroll
            for (int i = 0; i < 4; i++)
#pragma unroll
                for (int j = 0; j < 4; j++) acc[i][j] = fmaf(a4[i], b4[j], acc[i][j]);
        }
    }
#pragma unroll
    for (int j = 0; j < 4; j++) {
        int n = n0 + tx * 4 + j;
        float bv2 = bias[PERM ? rowp(n) : n];
#pragma unroll
        for (int i = 0; i < 4; i++) {
            int r = r0 + ty * 4 + i;
            out[(size_t)r * 2048 + n] = (OutT)(acc[i][j] + bv2);
        }
    }
}

// ---------------------------------------------------------------------------
// Persistent scan: encoder (1024 steps) then decoder (64 steps).
// 64 WGs x 512 threads.  WG w owns hidden units [8w, 8w+8) i.e. 32 permuted
// gate columns, for all 32 batches.  h / ht exchanged via depth-2 global
// rings with one device barrier per exchange.
// ---------------------------------------------------------------------------
__global__ __launch_bounds__(512) void scan_kernel(
    const f16* __restrict__ eg,      // [32768][2048] enc input gates (permuted cols), f16
    const float* __restrict__ dg,    // [2048][2048] dec y-part gates (permuted cols), f32
    const f16* __restrict__ Wenc,    // [2048][512]
    const f16* __restrict__ Wdih,    // [2048][512]  (ht part of dec_Wih)
    const f16* __restrict__ Wdhh,    // [2048][512]
    const f16* __restrict__ T2l,     // [512][512]
    const f16* __restrict__ CT2l,    // [512][1024]
    const float* __restrict__ wpt,   // [512] W_tan2pt
    f16* __restrict__ eh,            // [32][1024][512] encoder outputs
    f16* __restrict__ hb,            // ring 2 x [32][512]
    f16* __restrict__ htb,           // ring 2 x [32][512]
    f16* __restrict__ ctb,           // [32][512]
    float* __restrict__ ptacc,       // [64][32]
    float* __restrict__ dec_out,     // [2048][512]
    int* ctr) {
    const int w = blockIdx.x;
    const int tid = threadIdx.x;
    const int c  = tid >> 4;       // local gate col 0..31  (c = g*8+u)
    const int bq = tid & 15;
    const int b0 = bq, b1 = bq + 16;
    const int cg = w * 32 + c;     // global permuted col
    int bar = 0;

    __shared__ float gbuf[32][33];
    __shared__ float cst[8][32];
    __shared__ float zb[8][33];
    __shared__ float spart[64][9];
    __shared__ float sc[64];
    __shared__ float atw[64];
    __shared__ float pbuf[256][2];

    if (tid < 256) cst[tid >> 5][tid & 31] = 0.0f;

    const f16* Wrow = Wenc + (size_t)cg * 512;
    float ia0 = (float)eg[(size_t)b0 * 2048 + cg];
    float ia1 = (float)eg[(size_t)b1 * 2048 + cg];

    // ---------------- encoder ----------------
    for (int t = 0; t < 1024; t++) {
        const f16* hc = hb + ((t & 1) ? 16384 : 0);
        f16* hn       = hb + ((t & 1) ? 0 : 16384);
        float a0 = ia0, a1 = ia1;
        const f16* hp0 = hc + b0 * 512;
        const f16* hp1 = hc + b1 * 512;
#pragma unroll 4
        for (int k = 0; k < 512; k += 8) {
            V8 wv, h0, h1;
            wv.f4 = *(const float4*)(Wrow + k);
            h0.f4 = *(const float4*)(hp0 + k);
            h1.f4 = *(const float4*)(hp1 + k);
#pragma unroll
            for (int q = 0; q < 4; q++) {
                a0 = dot2f(wv.p[q], h0.p[q], a0);
                a1 = dot2f(wv.p[q], h1.p[q], a1);
            }
        }
        gbuf[c][b0] = a0;
        gbuf[c][b1] = a1;
        if (t < 1023) {   // prefetch next step's input gates during barrier wait
            ia0 = (float)eg[(size_t)((t + 1) * 32 + b0) * 2048 + cg];
            ia1 = (float)eg[(size_t)((t + 1) * 32 + b1) * 2048 + cg];
        }
        __syncthreads();
        if (tid < 256) {
            int u = tid >> 5, b = tid & 31;
            float gi = gbuf[u][b], gf = gbuf[8 + u][b];
            float gg = gbuf[16 + u][b], go = gbuf[24 + u][b];
            float cc = sigf(gf) * cst[u][b] + sigf(gi) * tanh_f(gg);
            float hh = sigf(go) * tanh_f(cc);
            cst[u][b] = cc;
            f16 h16 = (f16)hh;
            hn[b * 512 + w * 8 + u] = h16;
            eh[((size_t)b * 1024 + t) * 512 + w * 8 + u] = h16;
        }
        gbar(ctr, 64 * (++bar));
    }

    // ---------------- decoder ----------------
    for (int t = 0; t < 64; t++) {
        const f16* hc = hb + ((t & 1) ? 16384 : 0);
        f16* hn       = hb + ((t & 1) ? 0 : 16384);
        const f16* qc = htb + ((t & 1) ? 16384 : 0);
        f16* qn       = htb + ((t & 1) ? 0 : 16384);

        // stage A: LSTM gates (dec_ig + Wih_h . ht + Whh . h)
        {
            float a0 = dg[(size_t)(t * 32 + b0) * 2048 + cg];
            float a1 = dg[(size_t)(t * 32 + b1) * 2048 + cg];
            const f16* W1 = Wdih + (size_t)cg * 512;
            const f16* W2 = Wdhh + (size_t)cg * 512;
            const f16* q0 = qc + b0 * 512;
            const f16* q1 = qc + b1 * 512;
            const f16* h0 = hc + b0 * 512;
            const f16* h1 = hc + b1 * 512;
#pragma unroll 2
            for (int k = 0; k < 512; k += 8) {
                V8 wv1, wv2, x0, x1, y0, y1;
                wv1.f4 = *(const float4*)(W1 + k);
                x0.f4  = *(const float4*)(q0 + k);
                x1.f4  = *(const float4*)(q1 + k);
                wv2.f4 = *(const float4*)(W2 + k);
                y0.f4  = *(const float4*)(h0 + k);
                y1.f4  = *(const float4*)(h1 + k);
#pragma unroll
                for (int q = 0; q < 4; q++) {
                    a0 = dot2f(wv1.p[q], x0.p[q], a0);
                    a1 = dot2f(wv1.p[q], x1.p[q], a1);
                    a0 = dot2f(wv2.p[q], y0.p[q], a0);
                    a1 = dot2f(wv2.p[q], y1.p[q], a1);
                }
            }
            gbuf[c][b0] = a0;
            gbuf[c][b1] = a1;
            __syncthreads();
            if (tid < 256) {
                int u = tid >> 5, b = tid & 31;
                float gi = gbuf[u][b], gf = gbuf[8 + u][b];
                float gg = gbuf[16 + u][b], go = gbuf[24 + u][b];
                float cc = sigf(gf) * cst[u][b] + sigf(gi) * tanh_f(gg);
                float hh = sigf(go) * tanh_f(cc);
                cst[u][b] = cc;
                hn[b * 512 + w * 8 + u] = (f16)hh;
            }
        }
        gbar(ctr, 64 * (++bar));            // B1: yt visible
        const f16* yv = hn;

        // stage B: z = tanh(yt @ W_ht2tan.T) slice, pt partial dot
        if (tid < 256) {
            int u = tid >> 5, b = tid & 31;
            const f16* Tr = T2l + (size_t)(w * 8 + u) * 512;
            const f16* yb = yv + b * 512;
            float z = 0.0f;
#pragma unroll 4
            for (int k = 0; k < 512; k += 8) {
                V8 aa, bb;
                aa.f4 = *(const float4*)(Tr + k);
                bb.f4 = *(const float4*)(yb + k);
#pragma unroll
                for (int q = 0; q < 4; q++) z = dot2f(aa.p[q], bb.p[q], z);
            }
            zb[u][b] = tanh_f(z);
        }
        __syncthreads();
        if (tid < 32) {
            float pp = 0.0f;
#pragma unroll
            for (int u = 0; u < 8; u++) pp += zb[u][tid] * wpt[w * 8 + u];
            atomicAdd(&ptacc[t * 32 + tid], pp);
        }
        gbar(ctr, 64 * (++bar));            // B2: pt complete

        // stage C: attention (WG w < 32 owns batch b = w)
        if (w < 32) {
            const int b = w;
            float pt = sigf(ptacc[t * 32 + b]);
            float center = 1024.0f * pt;
            int ci = (int)floorf(center);
            int left = max(0, ci - 32);
            int right = min(1024, ci + 32);
            int win = right - left;
            int p = tid >> 3, seg = tid & 7;
            if (p < win) {
                const f16* yr = yv + b * 512 + seg * 64;
                const f16* er = eh + ((size_t)b * 1024 + (left + p)) * 512 + seg * 64;
                float s = 0.0f;
#pragma unroll
                for (int k = 0; k < 64; k += 8) {
                    V8 aa, bb;
                    aa.f4 = *(const float4*)(yr + k);
                    bb.f4 = *(const float4*)(er + k);
#pragma unroll
                    for (int q = 0; q < 4; q++) s = dot2f(aa.p[q], bb.p[q], s);
                }
                spart[p][seg] = s;
            }
            __syncthreads();
            if (tid < 64) {
                float s = -1e30f;
                if (tid < win) {
                    s = 0.0f;
#pragma unroll
                    for (int x = 0; x < 8; x++) s += spart[tid][x];
                }
                sc[tid] = s;
            }
            __syncthreads();
            float mx = -1e30f;
            for (int q2 = 0; q2 < 64; q2++) mx = fmaxf(mx, sc[q2]);
            float sum = 0.0f;
            for (int q2 = 0; q2 < 64; q2++) sum += __expf(sc[q2] - mx);
            if (tid < 64) {
                float sp = (float)(left + tid) - center;
                float gs = __expf(-(sp * sp) * (1.0f / 512.0f));
                atw[tid] = (tid < win) ? (__expf(sc[tid] - mx) / sum) * gs : 0.0f;
            }
            __syncthreads();
            {
                int j = tid;   // 0..511
                float a = 0.0f;
                const f16* ebase = eh + ((size_t)b * 1024 + left) * 512 + j;
                for (int q2 = 0; q2 < win; q2++) a += atw[q2] * (float)ebase[q2 * 512];
                ctb[b * 512 + j] = (f16)a;
            }
        }
        gbar(ctr, 64 * (++bar));            // B3: ct visible

        // stage D: ht_new = tanh([ct, yt] @ W_ct2ht.T) slice
        {
            int idx2 = tid >> 1, sg = tid & 1;
            int u = idx2 >> 5, b = idx2 & 31;
            const f16* Cr = CT2l + (size_t)(w * 8 + u) * 1024 + sg * 512;
            const f16* xr = sg ? (yv + b * 512) : (ctb + b * 512);
            float s = 0.0f;
#pragma unroll 4
            for (int k = 0; k < 512; k += 8) {
                V8 aa, bb;
                aa.f4 = *(const float4*)(Cr + k);
                bb.f4 = *(const float4*)(xr + k);
#pragma unroll
                for (int q = 0; q < 4; q++) s = dot2f(aa.p[q], bb.p[q], s);
            }
            pbuf[idx2][sg] = s;
        }
        __syncthreads();
        if (tid < 256) {
            int u = tid >> 5, b = tid & 31;
            float hv = tanh_f(pbuf[tid][0] + pbuf[tid][1]);
            qn[b * 512 + w * 8 + u] = (f16)hv;
            dec_out[(size_t)(t * 32 + b) * 512 + w * 8 + u] = hv;
        }
        gbar(ctr, 64 * (++bar));            // B4: ht ring ready
    }
}

// ---------------------------------------------------------------------------
// Projection + fused exp-sum / target-logit extraction.
// ---------------------------------------------------------------------------
__global__ __launch_bounds__(256) void proj_lse(
    const float* __restrict__ A,      // dec_out [2048][512]
    const float* __restrict__ W,      // [32000][512]
    const int* __restrict__ target,   // [65][32]
    float* __restrict__ se, float* __restrict__ tl) {
    __shared__ float As[16][65];
    __shared__ float Bs[16][65];
    __shared__ float eb[64][17];
    const int tid = threadIdx.x;
    const int v0 = blockIdx.x * 64;
    const int r0 = blockIdx.y * 64;
    const int tx = tid & 15, ty = tid >> 4;
    const int lk = tid & 3,  lr = tid >> 2;
    const float* arow = A + (size_t)(r0 + lr) * 512 + lk * 4;
    const float* brow = W + (size_t)(v0 + lr) * 512 + lk * 4;
    float acc[4][4] = {};
    for (int k0 = 0; k0 < 512; k0 += 16) {
        float4 av = *(const float4*)(arow + k0);
        float4 bv = *(const float4*)(brow + k0);
        __syncthreads();
        As[lk * 4 + 0][lr] = av.x; As[lk * 4 + 1][lr] = av.y;
        As[lk * 4 + 2][lr] = av.z; As[lk * 4 + 3][lr] = av.w;
        Bs[lk * 4 + 0][lr] = bv.x; Bs[lk * 4 + 1][lr] = bv.y;
        Bs[lk * 4 + 2][lr] = bv.z; Bs[lk * 4 + 3][lr] = bv.w;
        __syncthreads();
#pragma unroll
        for (int k = 0; k < 16; k++) {
            float a4[4], b4[4];
#pragma unroll
            for (int i = 0; i < 4; i++) a4[i] = As[k][ty * 4 + i];
#pragma unroll
            for (int j = 0; j < 4; j++) b4[j] = Bs[k][tx * 4 + j];
#pragma unroll
            for (int i = 0; i < 4; i++)
#pragma unroll
                for (int j = 0; j < 4; j++) acc[i][j] = fmaf(a4[i], b4[j], acc[i][j]);
        }
    }
#pragma unroll
    for (int i = 0; i < 4; i++) {
        int rg = r0 + ty * 4 + i;
        int tg = target[32 + rg];
        float es = 0.0f;
#pragma unroll
        for (int j = 0; j < 4; j++) {
            int n = v0 + tx * 4 + j;
            float l = acc[i][j];
            if (n == tg) atomicAdd(&tl[rg], l);
            es += __expf(l);
        }
        eb[ty * 4 + i][tx] = es;
    }
    __syncthreads();
    if (tid < 64) {
        float s = 0.0f;
#pragma unroll
        for (int x = 0; x < 16; x++) s += eb[tid][x];
        atomicAdd(&se[r0 + tid], s);
    }
}

__global__ void finalize_out(const float* __restrict__ se, const float* __restrict__ tl,
                             const int* __restrict__ target, float* __restrict__ out) {
    int b = threadIdx.x;
    if (b >= 32) return;
    float s = 0.0f;
    for (int t = 0; t < 64; t++) {
        int r = t * 32 + b;
        int tg = target[(t + 1) * 32 + b];
        if (tg != 0) s += tl[r] - logf(se[r]);
    }
    out[b] = s;
}

// ---------------------------------------------------------------------------
extern "C" void kernel_launch(void* const* d_in, const int* in_sizes, int n_in,
                              void* d_out, int out_size, void* d_ws, size_t ws_size,
                              hipStream_t stream) {
    const int*   source   = (const int*)  d_in[0];
    const int*   target   = (const int*)  d_in[1];
    const float* src_emb  = (const float*)d_in[2];
    const float* tar_emb  = (const float*)d_in[3];
    const float* enc_Wih  = (const float*)d_in[4];
    const float* enc_Whh  = (const float*)d_in[5];
    const float* enc_b    = (const float*)d_in[6];
    const float* dec_Wih  = (const float*)d_in[7];
    const float* dec_Whh  = (const float*)d_in[8];
    const float* dec_b    = (const float*)d_in[9];
    const float* W_ht2tan = (const float*)d_in[10];
    const float* W_tan2pt = (const float*)d_in[11];
    const float* W_ct2ht  = (const float*)d_in[12];
    const float* W_final  = (const float*)d_in[13];
    float* out = (float*)d_out;

    char* ws = (char*)d_ws;
    size_t off = 0;
    auto alloc = [&](size_t bytes) -> char* {
        char* p = ws + off;
        off = (off + bytes + 255) & ~(size_t)255;
        return p;
    };
    f16*   hb    = (f16*)  alloc((size_t)2 * 32 * 512 * 2);
    f16*   htb   = (f16*)  alloc((size_t)2 * 32 * 512 * 2);
    float* ptacc = (float*)alloc((size_t)64 * 32 * 4);
    float* se    = (float*)alloc((size_t)2048 * 4);
    float* tl    = (float*)alloc((size_t)2048 * 4);
    int*   ctr   = (int*)  alloc(256);
    size_t zero_end = off;
    f16*   eg    = (f16*)  alloc((size_t)32768 * 2048 * 2);
    float* dg    = (float*)alloc((size_t)2048 * 2048 * 4);
    f16*   eh    = (f16*)  alloc((size_t)32 * 1024 * 512 * 2);
    f16*   Wenc  = (f16*)  alloc((size_t)2048 * 512 * 2);
    f16*   Wdih  = (f16*)  alloc((size_t)2048 * 512 * 2);
    f16*   Wdhh  = (f16*)  alloc((size_t)2048 * 512 * 2);
    f16*   T2l   = (f16*)  alloc((size_t)512 * 512 * 2);
    f16*   CT2l  = (f16*)  alloc((size_t)512 * 1024 * 2);
    f16*   ctb   = (f16*)  alloc((size_t)32 * 512 * 2);
    float* dout  = (float*)alloc((size_t)2048 * 512 * 4);

    zero_ws<<<64, 256, 0, stream>>>((uint32_t*)ws, (int)(zero_end / 4));
    convert_weights<<<2048, 256, 0, stream>>>(enc_Whh, dec_Wih, dec_Whh, W_ht2tan, W_ct2ht,
                                              Wenc, Wdih, Wdhh, T2l, CT2l);
    gemm_gather<f16, 1><<<dim3(32, 512), 256, 0, stream>>>(src_emb, source, enc_Wih, 512, 0,
                                                           enc_b, eg);
    gemm_gather<float, 1><<<dim3(32, 32), 256, 0, stream>>>(tar_emb, target, dec_Wih, 1024, 0,
                                                            dec_b, dg);
    scan_kernel<<<64, 512, 0, stream>>>(eg, dg, Wenc, Wdih, Wdhh, T2l, CT2l, W_tan2pt,
                                        eh, hb, htb, ctb, ptacc, dout, ctr);
    proj_lse<<<dim3(500, 32), 256, 0, stream>>>(dout, W_final, target, se, tl);
    finalize_out<<<1, 64, 0, stream>>>(se, tl, target, out);
}

// Round 2
// 16160.370 us; speedup vs baseline: 3.2926x; 3.2926x over previous
//
#include <hip/hip_runtime.h>
#include <stdint.h>
#include <math.h>

// ---------------------------------------------------------------------------
// NMT seq2seq: encoder LSTM (S=1024) -> decoder LSTM + local attention (T=64)
// -> fused projection/log-softmax NLL.
//
// Scan strategy (round 2): 128 persistent WGs x 512 threads, each WG owns 16
// permuted gate columns (4 hidden units x 4 gates) for all 32 batches.
// Cross-WG h/ht/ct exchange via WRITE-THROUGH stores (global_store sc0 sc1,
// land at MALL) into UNIQUE per-step slots, synchronized by a fence-free
// device barrier: s_waitcnt vmcnt(0) -> s_barrier -> relaxed atomicAdd ->
// relaxed agent-scope poll.  No __threadfence anywhere in the hot loop
// (round-1 fences cost ~36us/step via L2 writeback+invalidate).
// ---------------------------------------------------------------------------

typedef _Float16 f16;
typedef _Float16 f16x2 __attribute__((ext_vector_type(2)));

union V8 { f16x2 p[4]; float4 f4; };

#define NWG 128

__device__ __forceinline__ float dot2f(f16x2 a, f16x2 b, float c) {
#if __has_builtin(__builtin_amdgcn_fdot2)
    return __builtin_amdgcn_fdot2(a, b, c, false);
#else
    return c + (float)a[0] * (float)b[0] + (float)a[1] * (float)b[1];
#endif
}

__device__ __forceinline__ float sigf(float x) { return 1.0f / (1.0f + __expf(-x)); }

__device__ __forceinline__ float tanh_f(float x) {
    float ax = fminf(fabsf(x), 12.0f);
    float e  = __expf(2.0f * ax);
    float r  = (e - 1.0f) / (e + 1.0f);
    return copysignf(r, x);
}

// write-through 2-byte store: bypasses L1/L2, lands at coherence point (MALL)
__device__ __forceinline__ void st_wt_b16(f16* p, f16 v) {
    union { f16 h; uint16_t u; } cv; cv.h = v;
    uint32_t d = cv.u;
    asm volatile("global_store_short %0, %1, off sc0 sc1" :: "v"(p), "v"(d) : "memory");
}

// Fence-free device barrier among NWG co-resident workgroups.
// Per-wave s_waitcnt vmcnt(0) guarantees this wave's write-through stores are
// at the coherence point before it enters s_barrier; thread 0's add is issued
// after all waves arrived, so counter==target implies all WGs' stores visible.
__device__ __forceinline__ void gbar(int* ctr, int target) {
    asm volatile("s_waitcnt vmcnt(0)" ::: "memory");
    __syncthreads();
    if (threadIdx.x == 0) {
        atomicAdd(ctr, 1);
        while (__hip_atomic_load(ctr, __ATOMIC_RELAXED, __HIP_MEMORY_SCOPE_AGENT) < target)
            __builtin_amdgcn_s_sleep(2);
    }
    __syncthreads();
}

// gate-column permutation: local col n (0..2047) -> original row in (4H).
// WG w owns units w*4..w*4+4; n = w*16 + g*4 + u  ->  g*512 + w*4 + u
__device__ __forceinline__ int rowp(int n) {
    return ((n >> 2) & 3) * 512 + (n >> 4) * 4 + (n & 3);
}

// ---------------------------------------------------------------------------
__global__ void zero_init(f16* h0, f16* q0, float* ptacc, float* se, float* tl,
                          int* ctr) {
    int i = blockIdx.x * blockDim.x + threadIdx.x;   // 16384 threads
    if (i < 16384) { h0[i] = (f16)0.0f; q0[i] = (f16)0.0f; }
    if (i < 2048)  { ptacc[i] = 0.0f; se[i] = 0.0f; tl[i] = 0.0f; }
    if (i == 0)    *ctr = 0;
}

// Convert / permute weights to f16 scan layouts.
__global__ void convert_weights(const float* __restrict__ encWhh,
                                const float* __restrict__ decWih,
                                const float* __restrict__ decWhh,
                                const float* __restrict__ ht2tan,
                                const float* __restrict__ ct2ht,
                                f16* __restrict__ Wenc, f16* __restrict__ Wdih,
                                f16* __restrict__ Wdhh, f16* __restrict__ T2l,
                                f16* __restrict__ CT2l) {
    const int NW = 2048 * 512;
    const int total = 3 * NW + 512 * 512 + 512 * 1024;
    int i = blockIdx.x * blockDim.x + threadIdx.x;
    int st = gridDim.x * blockDim.x;
    for (; i < total; i += st) {
        if (i < NW) {
            int n = i >> 9, k = i & 511;
            Wenc[i] = (f16)encWhh[rowp(n) * 512 + k];
        } else if (i < 2 * NW) {
            int j = i - NW; int n = j >> 9, k = j & 511;
            Wdih[j] = (f16)decWih[rowp(n) * 1024 + 512 + k];   // ht part of concat
        } else if (i < 3 * NW) {
            int j = i - 2 * NW; int n = j >> 9, k = j & 511;
            Wdhh[j] = (f16)decWhh[rowp(n) * 512 + k];
        } else if (i < 3 * NW + 512 * 512) {
            int j = i - 3 * NW;
            T2l[j] = (f16)ht2tan[j];
        } else {
            int j = i - 3 * NW - 512 * 512;
            CT2l[j] = (f16)ct2ht[j];
        }
    }
}

// Generic 64x64-tile f32 GEMM with gathered A rows (embedding lookup), bias,
// output-column permutation.  out[r][n] = emb[idx[r]] . W[rowp(n)] + b[rowp(n)]
template <typename OutT>
__global__ __launch_bounds__(256) void gemm_gather(
    const float* __restrict__ emb, const int* __restrict__ idx,
    const float* __restrict__ W, int ldw,
    const float* __restrict__ bias, OutT* __restrict__ out) {
    __shared__ float As[16][65];
    __shared__ float Bs[16][65];
    const int tid = threadIdx.x;
    const int n0 = blockIdx.x * 64;
    const int r0 = blockIdx.y * 64;
    const int tx = tid & 15, ty = tid >> 4;
    const int lk = tid & 3,  lr = tid >> 2;
    const float* arow = emb + (size_t)idx[r0 + lr] * 512 + lk * 4;
    const float* brow = W + (size_t)rowp(n0 + lr) * ldw + lk * 4;
    float acc[4][4] = {};
    for (int k0 = 0; k0 < 512; k0 += 16) {
        float4 av = *(const float4*)(arow + k0);
        float4 bv = *(const float4*)(brow + k0);
        __syncthreads();
        As[lk * 4 + 0][lr] = av.x; As[lk * 4 + 1][lr] = av.y;
        As[lk * 4 + 2][lr] = av.z; As[lk * 4 + 3][lr] = av.w;
        Bs[lk * 4 + 0][lr] = bv.x; Bs[lk * 4 + 1][lr] = bv.y;
        Bs[lk * 4 + 2][lr] = bv.z; Bs[lk * 4 + 3][lr] = bv.w;
        __syncthreads();
#pragma unroll
        for (int k = 0; k < 16; k++) {
            float a4[4], b4[4];
#pragma unroll
            for (int i = 0; i < 4; i++) a4[i] = As[k][ty * 4 + i];
#pragma unroll
            for (int j = 0; j < 4; j++) b4[j] = Bs[k][tx * 4 + j];
#pragma unroll
            for (int i = 0; i < 4; i++)
#pragma unroll
                for (int j = 0; j < 4; j++) acc[i][j] = fmaf(a4[i], b4[j], acc[i][j]);
        }
    }
#pragma unroll
    for (int j = 0; j < 4; j++) {
        int n = n0 + tx * 4 + j;
        float bv2 = bias[rowp(n)];
#pragma unroll
        for (int i = 0; i < 4; i++) {
            int r = r0 + ty * 4 + i;
            out[(size_t)r * 2048 + n] = (OutT)(acc[i][j] + bv2);
        }
    }
}

// ---------------------------------------------------------------------------
// Persistent scan: 128 WGs x 512 threads.
// ---------------------------------------------------------------------------
__global__ __launch_bounds__(512) void scan_kernel(
    const f16* __restrict__ eg,      // [32768][2048] enc input gates (perm cols)
    const float* __restrict__ dg,    // [2048][2048]  dec y-part gates (perm cols)
    const f16* __restrict__ Wenc,    // [2048][512]  (rows = permuted col order)
    const f16* __restrict__ Wdih,    // [2048][512]
    const f16* __restrict__ Wdhh,    // [2048][512]
    const f16* __restrict__ T2l,     // [512][512]
    const f16* __restrict__ CT2l,    // [512][1024]
    const float* __restrict__ wpt,   // [512]
    f16* __restrict__ eh,            // [32][1024][512] encoder outputs (write-through)
    f16* __restrict__ h_hist,        // [1089][32][512] slot0 zeroed
    f16* __restrict__ q_hist,        // [65][32][512]  slot0 zeroed
    f16* __restrict__ ctb,           // [64][32][512]
    float* __restrict__ ptacc,       // [64][32] zeroed
    float* __restrict__ dout,        // [2048][512]
    int* ctr) {
    const int w = blockIdx.x;
    const int tid = threadIdx.x;
    int bar = 0;

    // -------- LDS layout (total ~55.3 KB) --------
    __shared__ __align__(16) char smem[16640 + 33280 + 4096 + 2112 + 512];
    f16* W0s = (f16*)smem;                        // [16][520]  enc Whh / dec Wih slice
    f16* hst = (f16*)(smem + 16640);              // enc: hstage [32][520]
    f16* W1s = (f16*)(smem + 16640);              // dec: Wdhh slice [16][520]
    char* xtail = smem + 16640 + 16640;           // 16640 B free in dec mode
    float* zbS   = (float*)xtail;                 // [4][33]
    float* spart = (float*)(xtail + 544);         // [64][9]
    float* scS   = (float*)(xtail + 544 + 2304);  // [64]
    float* atwS  = (float*)(xtail + 544 + 2304 + 256);        // [64]
    float* dpart = (float*)(xtail + 544 + 2304 + 256 + 256);  // [128][4]
    float* part  = (float*)(smem + 49920);        // [2][16][32]
    float* gbufS = (float*)(smem + 53 * 1024 + 1792);  // = smem+56064? use explicit:
    gbufS = (float*)(smem + 49920 + 4096);        // [16][33] = 2112 B
    float* cstS  = (float*)(smem + 49920 + 4096 + 2112);  // [4][32]

    // -------- stage encoder weight slice into LDS; init cell state --------
    {
        int r = tid >> 5, seg = tid & 31;         // 16 rows x 32 segs x 32B
        const float4* s4 = (const float4*)(Wenc + (size_t)(w * 16 + r) * 512) + seg * 2;
        float4 a = s4[0], b2 = s4[1];
        float4* d4 = (float4*)(W0s + r * 520) + seg * 2;
        d4[0] = a; d4[1] = b2;
    }
    if (tid < 128) cstS[tid] = 0.0f;
    __syncthreads();

    const int ac = tid >> 5, ab = tid & 31;       // assembly mapping (c, b)
    const int kh = tid >> 8, cp = (tid >> 4) & 15, bp = tid & 15;  // dot mapping
    const int sb = tid >> 4, sj = tid & 15;       // staging mapping

    float egpf = (float)eg[(size_t)(w * 16 + ac) * 32 + ab];  // eg[t=0][c][b]... see layout below

    // NOTE eg layout from gemm is [r=t*32+b][n]: element (t,c,b) at (t*32+b)*2048 + w*16+c
    egpf = (float)eg[(size_t)(0 * 32 + ab) * 2048 + w * 16 + ac];

    // ---------------- encoder: 1024 steps, 1 barrier each ----------------
    for (int t = 0; t < 1024; t++) {
        const f16* hsrc = h_hist + (size_t)t * 16384;
        {   // stage h[t] (32KB) -> LDS, padded rows (520 f16)
            const float4* s4 = (const float4*)(hsrc + sb * 512) + sj * 4;
            float4 v0 = s4[0], v1 = s4[1], v2 = s4[2], v3 = s4[3];
            float4* d4 = (float4*)(hst + sb * 520) + sj * 4;
            d4[0] = v0; d4[1] = v1; d4[2] = v2; d4[3] = v3;
        }
        __syncthreads();
        {   // partial dot: col cp, batches bp/bp+16, k-half kh
            const f16* Wr = W0s + cp * 520 + kh * 256;
            const f16* h0 = hst + bp * 520 + kh * 256;
            const f16* h1 = hst + (bp + 16) * 520 + kh * 256;
            float a0 = 0.0f, a1 = 0.0f;
#pragma unroll 8
            for (int k = 0; k < 256; k += 8) {
                V8 wv, x0, x1;
                wv.f4 = *(const float4*)(Wr + k);
                x0.f4 = *(const float4*)(h0 + k);
                x1.f4 = *(const float4*)(h1 + k);
#pragma unroll
                for (int q = 0; q < 4; q++) {
                    a0 = dot2f(wv.p[q], x0.p[q], a0);
                    a1 = dot2f(wv.p[q], x1.p[q], a1);
                }
            }
            float* pp = part + (kh * 16 + cp) * 32;
            pp[bp] = a0; pp[bp + 16] = a1;
        }
        __syncthreads();
        // assembly: gate[c][b] = part0 + part1 + eg
        gbufS[ac * 33 + ab] = part[ac * 32 + ab] + part[(16 + ac) * 32 + ab] + egpf;
        if (t < 1023)
            egpf = (float)eg[(size_t)((t + 1) * 32 + ab) * 2048 + w * 16 + ac];
        __syncthreads();
        if (tid < 128) {  // activation: b = tid>>2, u = tid&3
            int b = tid >> 2, u = tid & 3;
            float gi = gbufS[u * 33 + b];
            float gf = gbufS[(4 + u) * 33 + b];
            float gg = gbufS[(8 + u) * 33 + b];
            float go = gbufS[(12 + u) * 33 + b];
            float cc = sigf(gf) * cstS[u * 32 + b] + sigf(gi) * tanh_f(gg);
            float hh = sigf(go) * tanh_f(cc);
            cstS[u * 32 + b] = cc;
            f16 h16 = (f16)hh;
            st_wt_b16(h_hist + (size_t)(t + 1) * 16384 + b * 512 + w * 4 + u, h16);
            st_wt_b16(eh + ((size_t)b * 1024 + t) * 512 + w * 4 + u, h16);
        }
        gbar(ctr, NWG * (++bar));
    }

    // -------- stage decoder weight slices into LDS (overwrites hstage) --------
    __syncthreads();
    {
        int r = tid >> 5, seg = tid & 31;
        const float4* s1 = (const float4*)(Wdih + (size_t)(w * 16 + r) * 512) + seg * 2;
        float4 a1 = s1[0], a2 = s1[1];
        const float4* s2 = (const float4*)(Wdhh + (size_t)(w * 16 + r) * 512) + seg * 2;
        float4 b1 = s2[0], b2 = s2[1];
        float4* d1 = (float4*)(W0s + r * 520) + seg * 2;
        float4* d2 = (float4*)(W1s + r * 520) + seg * 2;
        d1[0] = a1; d1[1] = a2;
        d2[0] = b1; d2[1] = b2;
    }
    __syncthreads();

    // ---------------- decoder: 64 steps, 4 barriers each ----------------
    for (int t = 0; t < 64; t++) {
        const f16* hsrc = h_hist + (size_t)(1024 + t) * 16384;   // prev h
        const f16* qsrc = q_hist + (size_t)t * 16384;            // prev ht
        f16* hdst = h_hist + (size_t)(1025 + t) * 16384;         // yt

        // ---- stage A: gates = dg + Wih_h.ht + Whh.h ----
        {
            const f16* W1r = W0s + cp * 520 + kh * 256;
            const f16* W2r = W1s + cp * 520 + kh * 256;
            const f16* q0 = qsrc + bp * 512 + kh * 256;
            const f16* q1 = qsrc + (bp + 16) * 512 + kh * 256;
            const f16* h0 = hsrc + bp * 512 + kh * 256;
            const f16* h1 = hsrc + (bp + 16) * 512 + kh * 256;
            float a0 = 0.0f, a1 = 0.0f;
#pragma unroll 2
            for (int k = 0; k < 256; k += 8) {
                V8 w1, w2, x0, x1, y0, y1;
                w1.f4 = *(const float4*)(W1r + k);
                w2.f4 = *(const float4*)(W2r + k);
                x0.f4 = *(const float4*)(q0 + k);
                x1.f4 = *(const float4*)(q1 + k);
                y0.f4 = *(const float4*)(h0 + k);
                y1.f4 = *(const float4*)(h1 + k);
#pragma unroll
                for (int q = 0; q < 4; q++) {
                    a0 = dot2f(w1.p[q], x0.p[q], a0);
                    a1 = dot2f(w1.p[q], x1.p[q], a1);
                    a0 = dot2f(w2.p[q], y0.p[q], a0);
                    a1 = dot2f(w2.p[q], y1.p[q], a1);
                }
            }
            float* pp = part + (kh * 16 + cp) * 32;
            pp[bp] = a0; pp[bp + 16] = a1;
        }
        __syncthreads();
        gbufS[ac * 33 + ab] = part[ac * 32 + ab] + part[(16 + ac) * 32 + ab]
                            + dg[(size_t)(t * 32 + ab) * 2048 + w * 16 + ac];
        __syncthreads();
        if (tid < 128) {
            int b = tid >> 2, u = tid & 3;
            float gi = gbufS[u * 33 + b];
            float gf = gbufS[(4 + u) * 33 + b];
            float gg = gbufS[(8 + u) * 33 + b];
            float go = gbufS[(12 + u) * 33 + b];
            float cc = sigf(gf) * cstS[u * 32 + b] + sigf(gi) * tanh_f(gg);
            float hh = sigf(go) * tanh_f(cc);
            cstS[u * 32 + b] = cc;
            st_wt_b16(hdst + b * 512 + w * 4 + u, (f16)hh);
        }
        gbar(ctr, NWG * (++bar));            // B1: yt visible
        const f16* yv = hdst;

        // ---- stage B: z = tanh(yt @ W_ht2tan.T) slice; pt partial dot ----
        {
            int kq = tid >> 7, u = (tid >> 5) & 3, b = tid & 31;
            const f16* Tr = T2l + (size_t)(w * 4 + u) * 512 + kq * 128;
            const f16* yb = yv + b * 512 + kq * 128;
            float z = 0.0f;
#pragma unroll 4
            for (int k = 0; k < 128; k += 8) {
                V8 aa, bb;
                aa.f4 = *(const float4*)(Tr + k);
                bb.f4 = *(const float4*)(yb + k);
#pragma unroll
                for (int q = 0; q < 4; q++) z = dot2f(aa.p[q], bb.p[q], z);
            }
            dpart[(u * 32 + b) * 4 + kq] = z;
        }
        __syncthreads();
        if (tid < 128) {
            int u = tid >> 5, b = tid & 31;
            float z = dpart[tid * 4] + dpart[tid * 4 + 1] + dpart[tid * 4 + 2] + dpart[tid * 4 + 3];
            zbS[u * 33 + b] = tanh_f(z);
        }
        __syncthreads();
        if (tid < 32) {
            float pp = zbS[tid] * wpt[w * 4]
                     + zbS[33 + tid] * wpt[w * 4 + 1]
                     + zbS[66 + tid] * wpt[w * 4 + 2]
                     + zbS[99 + tid] * wpt[w * 4 + 3];
            atomicAdd(&ptacc[t * 32 + tid], pp);
        }
        gbar(ctr, NWG * (++bar));            // B2: pt complete

        // ---- stage C: local attention (WG b < 32 owns batch b) ----
        if (w < 32) {
            const int b = w;
            float pt = sigf(__hip_atomic_load(&ptacc[t * 32 + b], __ATOMIC_RELAXED,
                                              __HIP_MEMORY_SCOPE_AGENT));
            float center = 1024.0f * pt;
            int ci = (int)floorf(center);
            int left = max(0, ci - 32);
            int right = min(1024, ci + 32);
            int win = right - left;
            int p = tid >> 3, seg = tid & 7;
            if (p < win) {
                const f16* yr = yv + b * 512 + seg * 64;
                const f16* er = eh + ((size_t)b * 1024 + (left + p)) * 512 + seg * 64;
                float s = 0.0f;
#pragma unroll
                for (int k = 0; k < 64; k += 8) {
                    V8 aa, bb;
                    aa.f4 = *(const float4*)(yr + k);
                    bb.f4 = *(const float4*)(er + k);
#pragma unroll
                    for (int q = 0; q < 4; q++) s = dot2f(aa.p[q], bb.p[q], s);
                }
                spart[p * 9 + seg] = s;
            }
            __syncthreads();
            if (tid < 64) {
                float s = -1e30f;
                if (tid < win) {
                    s = 0.0f;
#pragma unroll
                    for (int x = 0; x < 8; x++) s += spart[tid * 9 + x];
                }
                scS[tid] = s;
            }
            __syncthreads();
            float mx = -1e30f;
            for (int q2 = 0; q2 < 64; q2++) mx = fmaxf(mx, scS[q2]);
            float sum = 0.0f;
            for (int q2 = 0; q2 < 64; q2++) sum += __expf(scS[q2] - mx);
            if (tid < 64) {
                float sp = (float)(left + tid) - center;
                float gs = __expf(-(sp * sp) * (1.0f / 512.0f));
                atwS[tid] = (tid < win) ? (__expf(scS[tid] - mx) / sum) * gs : 0.0f;
            }
            __syncthreads();
            {
                int j = tid;   // 0..511
                float a = 0.0f;
                const f16* ebase = eh + ((size_t)b * 1024 + left) * 512 + j;
                for (int q2 = 0; q2 < win; q2++) a += atwS[q2] * (float)ebase[q2 * 512];
                st_wt_b16(ctb + (size_t)t * 16384 + b * 512 + j, (f16)a);
            }
        }
        gbar(ctr, NWG * (++bar));            // B3: ct visible

        // ---- stage D: ht_new = tanh([ct, yt] @ W_ct2ht.T) slice ----
        {
            int idx = tid >> 2, q4 = tid & 3;   // idx = b*4+u
            int b = idx >> 2, u = idx & 3;
            const f16* Cr = CT2l + (size_t)(w * 4 + u) * 1024 + q4 * 256;
            const f16* xr = (q4 < 2)
                ? (ctb + (size_t)t * 16384 + b * 512 + q4 * 256)
                : (yv + b * 512 + (q4 - 2) * 256);
            float s = 0.0f;
#pragma unroll 4
            for (int k = 0; k < 256; k += 8) {
                V8 aa, bb;
                aa.f4 = *(const float4*)(Cr + k);
                bb.f4 = *(const float4*)(xr + k);
#pragma unroll
                for (int q = 0; q < 4; q++) s = dot2f(aa.p[q], bb.p[q], s);
            }
            dpart[idx * 4 + q4] = s;
        }
        __syncthreads();
        if (tid < 128) {
            int b = tid >> 2, u = tid & 3;
            float hv = tanh_f(dpart[tid * 4] + dpart[tid * 4 + 1] +
                              dpart[tid * 4 + 2] + dpart[tid * 4 + 3]);
            st_wt_b16(q_hist + (size_t)(t + 1) * 16384 + b * 512 + w * 4 + u, (f16)hv);
            dout[(size_t)(t * 32 + b) * 512 + w * 4 + u] = hv;  // regular: next kernel
        }
        gbar(ctr, NWG * (++bar));            // B4: ht ring ready
    }
}

// ---------------------------------------------------------------------------
// Projection + fused exp-sum / target-logit extraction.
// ---------------------------------------------------------------------------
__global__ __launch_bounds__(256) void proj_lse(
    const float* __restrict__ A,      // dec_out [2048][512]
    const float* __restrict__ W,      // [32000][512]
    const int* __restrict__ target,   // [65][32]
    float* __restrict__ se, float* __restrict__ tl) {
    __shared__ float As[16][65];
    __shared__ float Bs[16][65];
    __shared__ float eb[64][17];
    const int tid = threadIdx.x;
    const int v0 = blockIdx.x * 64;
    const int r0 = blockIdx.y * 64;
    const int tx = tid & 15, ty = tid >> 4;
    const int lk = tid & 3,  lr = tid >> 2;
    const float* arow = A + (size_t)(r0 + lr) * 512 + lk * 4;
    const float* brow = W + (size_t)(v0 + lr) * 512 + lk * 4;
    float acc[4][4] = {};
    for (int k0 = 0; k0 < 512; k0 += 16) {
        float4 av = *(const float4*)(arow + k0);
        float4 bv = *(const float4*)(brow + k0);
        __syncthreads();
        As[lk * 4 + 0][lr] = av.x; As[lk * 4 + 1][lr] = av.y;
        As[lk * 4 + 2][lr] = av.z; As[lk * 4 + 3][lr] = av.w;
        Bs[lk * 4 + 0][lr] = bv.x; Bs[lk * 4 + 1][lr] = bv.y;
        Bs[lk * 4 + 2][lr] = bv.z; Bs[lk * 4 + 3][lr] = bv.w;
        __syncthreads();
#pragma unroll
        for (int k = 0; k < 16; k++) {
            float a4[4], b4[4];
#pragma unroll
            for (int i = 0; i < 4; i++) a4[i] = As[k][ty * 4 + i];
#pragma unroll
            for (int j = 0; j < 4; j++) b4[j] = Bs[k][tx * 4 + j];
#pragma unroll
            for (int i = 0; i < 4; i++)
#pragma unroll
                for (int j = 0; j < 4; j++) acc[i][j] = fmaf(a4[i], b4[j], acc[i][j]);
        }
    }
#pragma unroll
    for (int i = 0; i < 4; i++) {
        int rg = r0 + ty * 4 + i;
        int tg = target[32 + rg];
        float es = 0.0f;
#pragma unroll
        for (int j = 0; j < 4; j++) {
            int n = v0 + tx * 4 + j;
            float l = acc[i][j];
            if (n == tg) atomicAdd(&tl[rg], l);
            es += __expf(l);
        }
        eb[ty * 4 + i][tx] = es;
    }
    __syncthreads();
    if (tid < 64) {
        float s = 0.0f;
#pragma unroll
        for (int x = 0; x < 16; x++) s += eb[tid][x];
        atomicAdd(&se[r0 + tid], s);
    }
}

__global__ void finalize_out(const float* __restrict__ se, const float* __restrict__ tl,
                             const int* __restrict__ target, float* __restrict__ out) {
    int b = threadIdx.x;
    if (b >= 32) return;
    float s = 0.0f;
    for (int t = 0; t < 64; t++) {
        int r = t * 32 + b;
        int tg = target[(t + 1) * 32 + b];
        if (tg != 0) s += tl[r] - logf(se[r]);
    }
    out[b] = s;
}

// ---------------------------------------------------------------------------
extern "C" void kernel_launch(void* const* d_in, const int* in_sizes, int n_in,
                              void* d_out, int out_size, void* d_ws, size_t ws_size,
                              hipStream_t stream) {
    const int*   source   = (const int*)  d_in[0];
    const int*   target   = (const int*)  d_in[1];
    const float* src_emb  = (const float*)d_in[2];
    const float* tar_emb  = (const float*)d_in[3];
    const float* enc_Wih  = (const float*)d_in[4];
    const float* enc_Whh  = (const float*)d_in[5];
    const float* enc_b    = (const float*)d_in[6];
    const float* dec_Wih  = (const float*)d_in[7];
    const float* dec_Whh  = (const float*)d_in[8];
    const float* dec_b    = (const float*)d_in[9];
    const float* W_ht2tan = (const float*)d_in[10];
    const float* W_tan2pt = (const float*)d_in[11];
    const float* W_ct2ht  = (const float*)d_in[12];
    const float* W_final  = (const float*)d_in[13];
    float* out = (float*)d_out;

    char* ws = (char*)d_ws;
    size_t off = 0;
    auto alloc = [&](size_t bytes) -> char* {
        char* p = ws + off;
        off = (off + bytes + 255) & ~(size_t)255;
        return p;
    };
    f16*   h_hist = (f16*)  alloc((size_t)1089 * 16384 * 2);   // 34.9 MB
    f16*   q_hist = (f16*)  alloc((size_t)65 * 16384 * 2);
    f16*   ctb    = (f16*)  alloc((size_t)64 * 16384 * 2);
    float* ptacc  = (float*)alloc((size_t)64 * 32 * 4);
    float* se     = (float*)alloc((size_t)2048 * 4);
    float* tl     = (float*)alloc((size_t)2048 * 4);
    int*   ctr    = (int*)  alloc(256);
    f16*   eg     = (f16*)  alloc((size_t)32768 * 2048 * 2);
    float* dg     = (float*)alloc((size_t)2048 * 2048 * 4);
    f16*   eh     = (f16*)  alloc((size_t)32 * 1024 * 512 * 2);
    f16*   Wenc   = (f16*)  alloc((size_t)2048 * 512 * 2);
    f16*   Wdih   = (f16*)  alloc((size_t)2048 * 512 * 2);
    f16*   Wdhh   = (f16*)  alloc((size_t)2048 * 512 * 2);
    f16*   T2l    = (f16*)  alloc((size_t)512 * 512 * 2);
    f16*   CT2l   = (f16*)  alloc((size_t)512 * 1024 * 2);
    float* dout   = (float*)alloc((size_t)2048 * 512 * 4);

    zero_init<<<64, 256, 0, stream>>>(h_hist, q_hist, ptacc, se, tl, ctr);
    convert_weights<<<2048, 256, 0, stream>>>(enc_Whh, dec_Wih, dec_Whh, W_ht2tan, W_ct2ht,
                                              Wenc, Wdih, Wdhh, T2l, CT2l);
    gemm_gather<f16><<<dim3(32, 512), 256, 0, stream>>>(src_emb, source, enc_Wih, 512,
                                                        enc_b, eg);
    gemm_gather<float><<<dim3(32, 32), 256, 0, stream>>>(tar_emb, target, dec_Wih, 1024,
                                                         dec_b, dg);
    scan_kernel<<<NWG, 512, 0, stream>>>(eg, dg, Wenc, Wdih, Wdhh, T2l, CT2l, W_tan2pt,
                                         eh, h_hist, q_hist, ctb, ptacc, dout, ctr);
    proj_lse<<<dim3(500, 32), 256, 0, stream>>>(dout, W_final, target, se, tl);
    finalize_out<<<1, 64, 0, stream>>>(se, tl, target, out);
}

// Round 3
// 12498.772 us; speedup vs baseline: 4.2572x; 1.2930x over previous
//
#include <hip/hip_runtime.h>
#include <stdint.h>
#include <math.h>

// ---------------------------------------------------------------------------
// NMT seq2seq: encoder LSTM (S=1024) -> decoder LSTM + local attention (T=64)
// -> fused projection/log-softmax NLL.
//
// Round 3: distributed fence-free device barrier (per-WG write-through flag +
// all-WG parallel poll of 128 flags; NO atomics -- round-2's single atomic
// counter serialized 128 RMWs/step at the MALL ~= 10us/step).  ptacc atomics
// replaced by write-through partials in unique-per-step slots.  eg/dg gate
// loads prefetched at iteration top so pre-barrier vmcnt(0) is cheap.
// ---------------------------------------------------------------------------

typedef _Float16 f16;
typedef _Float16 f16x2 __attribute__((ext_vector_type(2)));

union V8 { f16x2 p[4]; float4 f4; };

#define NWG 128
#define FLAG_STRIDE 32   // ints; 128B spacing -> one MALL line per WG

__device__ __forceinline__ float dot2f(f16x2 a, f16x2 b, float c) {
#if __has_builtin(__builtin_amdgcn_fdot2)
    return __builtin_amdgcn_fdot2(a, b, c, false);
#else
    return c + (float)a[0] * (float)b[0] + (float)a[1] * (float)b[1];
#endif
}

__device__ __forceinline__ float sigf(float x) { return 1.0f / (1.0f + __expf(-x)); }

__device__ __forceinline__ float tanh_f(float x) {
    float ax = fminf(fabsf(x), 12.0f);
    float e  = __expf(2.0f * ax);
    float r  = (e - 1.0f) / (e + 1.0f);
    return copysignf(r, x);
}

// write-through stores: bypass L1/L2, land at coherence point (MALL)
__device__ __forceinline__ void st_wt_b16(f16* p, f16 v) {
    union { f16 h; uint16_t u; } cv; cv.h = v;
    uint32_t d = cv.u;
    asm volatile("global_store_short %0, %1, off sc0 sc1" :: "v"(p), "v"(d) : "memory");
}
__device__ __forceinline__ void st_wt_b32(int* p, int v) {
    asm volatile("global_store_dword %0, %1, off sc0 sc1" :: "v"(p), "v"(v) : "memory");
}
__device__ __forceinline__ void st_wt_f32(float* p, float v) {
    union { float f; int i; } cv; cv.f = v;
    asm volatile("global_store_dword %0, %1, off sc0 sc1" :: "v"(p), "v"(cv.i) : "memory");
}

// two L1/L2-bypassing dword loads + single wait (parallel scatter-gather)
__device__ __forceinline__ void ld2_bypass(const int* p0, const int* p1, int& v0, int& v1) {
    asm volatile("global_load_dword %0, %2, off sc0 sc1\n\t"
                 "global_load_dword %1, %3, off sc0 sc1\n\t"
                 "s_waitcnt vmcnt(0)"
                 : "=&v"(v0), "=&v"(v1)
                 : "v"(p0), "v"(p1)
                 : "memory");
}

// Distributed fence-free device barrier among NWG co-resident workgroups.
// Per-wave s_waitcnt vmcnt(0) + s_barrier => all this WG's write-through data
// stores are at the MALL before lane 0 publishes the arrival flag.  Wave 0's
// 64 lanes then poll all 128 flags in parallel (2 bypass loads each).
__device__ __forceinline__ void gbar(int* flags, int w, int step) {
    asm volatile("s_waitcnt vmcnt(0)" ::: "memory");
    __syncthreads();
    if (threadIdx.x < 64) {
        if (threadIdx.x == 0) st_wt_b32(flags + w * FLAG_STRIDE, step);
        const int* f0 = flags + (threadIdx.x * 2) * FLAG_STRIDE;
        const int* f1 = flags + (threadIdx.x * 2 + 1) * FLAG_STRIDE;
        for (;;) {
            int v0, v1;
            ld2_bypass(f0, f1, v0, v1);
            if (__all(v0 >= step && v1 >= step)) break;
            __builtin_amdgcn_s_sleep(1);
        }
    }
    __syncthreads();
}

// gate-column permutation: local col n (0..2047) -> original row in (4H).
// WG w owns units w*4..w*4+4; n = w*16 + g*4 + u  ->  g*512 + w*4 + u
__device__ __forceinline__ int rowp(int n) {
    return ((n >> 2) & 3) * 512 + (n >> 4) * 4 + (n & 3);
}

// ---------------------------------------------------------------------------
__global__ void zero_init(f16* h0, f16* q0, int* flags, float* se, float* tl) {
    int i = blockIdx.x * blockDim.x + threadIdx.x;   // 16384 threads
    if (i < 16384) { h0[i] = (f16)0.0f; q0[i] = (f16)0.0f; }
    if (i < 2048)  { se[i] = 0.0f; tl[i] = 0.0f; }
    if (i < NWG * FLAG_STRIDE) flags[i] = 0;
}

// Convert / permute weights to f16 scan layouts.
__global__ void convert_weights(const float* __restrict__ encWhh,
                                const float* __restrict__ decWih,
                                const float* __restrict__ decWhh,
                                const float* __restrict__ ht2tan,
                                const float* __restrict__ ct2ht,
                                f16* __restrict__ Wenc, f16* __restrict__ Wdih,
                                f16* __restrict__ Wdhh, f16* __restrict__ T2l,
                                f16* __restrict__ CT2l) {
    const int NW = 2048 * 512;
    const int total = 3 * NW + 512 * 512 + 512 * 1024;
    int i = blockIdx.x * blockDim.x + threadIdx.x;
    int st = gridDim.x * blockDim.x;
    for (; i < total; i += st) {
        if (i < NW) {
            int n = i >> 9, k = i & 511;
            Wenc[i] = (f16)encWhh[rowp(n) * 512 + k];
        } else if (i < 2 * NW) {
            int j = i - NW; int n = j >> 9, k = j & 511;
            Wdih[j] = (f16)decWih[rowp(n) * 1024 + 512 + k];   // ht part of concat
        } else if (i < 3 * NW) {
            int j = i - 2 * NW; int n = j >> 9, k = j & 511;
            Wdhh[j] = (f16)decWhh[rowp(n) * 512 + k];
        } else if (i < 3 * NW + 512 * 512) {
            int j = i - 3 * NW;
            T2l[j] = (f16)ht2tan[j];
        } else {
            int j = i - 3 * NW - 512 * 512;
            CT2l[j] = (f16)ct2ht[j];
        }
    }
}

// Generic 64x64-tile f32 GEMM with gathered A rows (embedding lookup), bias,
// output-column permutation.  out[r][n] = emb[idx[r]] . W[rowp(n)] + b[rowp(n)]
template <typename OutT>
__global__ __launch_bounds__(256) void gemm_gather(
    const float* __restrict__ emb, const int* __restrict__ idx,
    const float* __restrict__ W, int ldw,
    const float* __restrict__ bias, OutT* __restrict__ out) {
    __shared__ float As[16][65];
    __shared__ float Bs[16][65];
    const int tid = threadIdx.x;
    const int n0 = blockIdx.x * 64;
    const int r0 = blockIdx.y * 64;
    const int tx = tid & 15, ty = tid >> 4;
    const int lk = tid & 3,  lr = tid >> 2;
    const float* arow = emb + (size_t)idx[r0 + lr] * 512 + lk * 4;
    const float* brow = W + (size_t)rowp(n0 + lr) * ldw + lk * 4;
    float acc[4][4] = {};
    for (int k0 = 0; k0 < 512; k0 += 16) {
        float4 av = *(const float4*)(arow + k0);
        float4 bv = *(const float4*)(brow + k0);
        __syncthreads();
        As[lk * 4 + 0][lr] = av.x; As[lk * 4 + 1][lr] = av.y;
        As[lk * 4 + 2][lr] = av.z; As[lk * 4 + 3][lr] = av.w;
        Bs[lk * 4 + 0][lr] = bv.x; Bs[lk * 4 + 1][lr] = bv.y;
        Bs[lk * 4 + 2][lr] = bv.z; Bs[lk * 4 + 3][lr] = bv.w;
        __syncthreads();
#pragma unroll
        for (int k = 0; k < 16; k++) {
            float a4[4], b4[4];
#pragma unroll
            for (int i = 0; i < 4; i++) a4[i] = As[k][ty * 4 + i];
#pragma unroll
            for (int j = 0; j < 4; j++) b4[j] = Bs[k][tx * 4 + j];
#pragma unroll
            for (int i = 0; i < 4; i++)
#pragma unroll
                for (int j = 0; j < 4; j++) acc[i][j] = fmaf(a4[i], b4[j], acc[i][j]);
        }
    }
#pragma unroll
    for (int j = 0; j < 4; j++) {
        int n = n0 + tx * 4 + j;
        float bv2 = bias[rowp(n)];
#pragma unroll
        for (int i = 0; i < 4; i++) {
            int r = r0 + ty * 4 + i;
            out[(size_t)r * 2048 + n] = (OutT)(acc[i][j] + bv2);
        }
    }
}

// ---------------------------------------------------------------------------
// Persistent scan: 128 WGs x 512 threads.
// ---------------------------------------------------------------------------
__global__ __launch_bounds__(512) void scan_kernel(
    const f16* __restrict__ eg,      // [32768][2048] enc input gates (perm cols)
    const float* __restrict__ dg,    // [2048][2048]  dec y-part gates (perm cols)
    const f16* __restrict__ Wenc,    // [2048][512]  (rows = permuted col order)
    const f16* __restrict__ Wdih,    // [2048][512]
    const f16* __restrict__ Wdhh,    // [2048][512]
    const f16* __restrict__ T2l,     // [512][512]
    const f16* __restrict__ CT2l,    // [512][1024]
    const float* __restrict__ wpt,   // [512]
    f16* __restrict__ eh,            // [32][1024][512] encoder outputs (write-through)
    f16* __restrict__ h_hist,        // [1089][32][512] slot0 zeroed
    f16* __restrict__ q_hist,        // [65][32][512]  slot0 zeroed
    f16* __restrict__ ctb,           // [64][32][512]
    float* __restrict__ ppart,       // [64][32][128] pt partials (write-through)
    float* __restrict__ dout,        // [2048][512]
    int* flags) {
    const int w = blockIdx.x;
    const int tid = threadIdx.x;
    int bar = 0;

    // -------- LDS layout --------
    __shared__ __align__(16) char smem[16640 + 33280 + 4096 + 2112 + 512];
    f16* W0s = (f16*)smem;                        // [16][520]  enc Whh / dec Wih slice
    f16* hst = (f16*)(smem + 16640);              // enc: hstage [32][520]
    f16* W1s = (f16*)(smem + 16640);              // dec: Wdhh slice [16][520]
    char* xtail = smem + 16640 + 16640;           // 16640 B free in dec mode
    float* zbS   = (float*)xtail;                 // [4][33]
    float* spart = (float*)(xtail + 544);         // [64][9]
    float* scS   = (float*)(xtail + 544 + 2304);  // [64]
    float* atwS  = (float*)(xtail + 544 + 2304 + 256);        // [64]
    float* dpart = (float*)(xtail + 544 + 2304 + 256 + 256);  // [128][4]
    float* ptS   = (float*)(xtail + 544 + 2304 + 256 + 256 + 2048);  // [1]
    float* part  = (float*)(smem + 49920);        // [2][16][32]
    float* gbufS = (float*)(smem + 49920 + 4096); // [16][33]
    float* cstS  = (float*)(smem + 49920 + 4096 + 2112);  // [4][32]

    // -------- stage encoder weight slice into LDS; init cell state --------
    {
        int r = tid >> 5, seg = tid & 31;         // 16 rows x 32 segs x 32B
        const float4* s4 = (const float4*)(Wenc + (size_t)(w * 16 + r) * 512) + seg * 2;
        float4 a = s4[0], b2 = s4[1];
        float4* d4 = (float4*)(W0s + r * 520) + seg * 2;
        d4[0] = a; d4[1] = b2;
    }
    if (tid < 128) cstS[tid] = 0.0f;
    __syncthreads();

    const int ac = tid >> 5, ab = tid & 31;       // assembly mapping (c, b)
    const int kh = tid >> 8, cp = (tid >> 4) & 15, bp = tid & 15;  // dot mapping
    const int sb = tid >> 4, sj = tid & 15;       // staging mapping

    float egpf = (float)eg[(size_t)(0 * 32 + ab) * 2048 + w * 16 + ac];

    // ---------------- encoder: 1024 steps, 1 barrier each ----------------
    for (int t = 0; t < 1024; t++) {
        float eg_next = 0.0f;
        if (t < 1023)    // prefetch next step's gate early; vmcnt drains by gbar
            eg_next = (float)eg[(size_t)((t + 1) * 32 + ab) * 2048 + w * 16 + ac];
        const f16* hsrc = h_hist + (size_t)t * 16384;
        {   // stage h[t] (32KB) -> LDS, padded rows (520 f16)
            const float4* s4 = (const float4*)(hsrc + sb * 512) + sj * 4;
            float4 v0 = s4[0], v1 = s4[1], v2 = s4[2], v3 = s4[3];
            float4* d4 = (float4*)(hst + sb * 520) + sj * 4;
            d4[0] = v0; d4[1] = v1; d4[2] = v2; d4[3] = v3;
        }
        __syncthreads();
        {   // partial dot: col cp, batches bp/bp+16, k-half kh
            const f16* Wr = W0s + cp * 520 + kh * 256;
            const f16* h0 = hst + bp * 520 + kh * 256;
            const f16* h1 = hst + (bp + 16) * 520 + kh * 256;
            float a0 = 0.0f, a1 = 0.0f;
#pragma unroll 8
            for (int k = 0; k < 256; k += 8) {
                V8 wv, x0, x1;
                wv.f4 = *(const float4*)(Wr + k);
                x0.f4 = *(const float4*)(h0 + k);
                x1.f4 = *(const float4*)(h1 + k);
#pragma unroll
                for (int q = 0; q < 4; q++) {
                    a0 = dot2f(wv.p[q], x0.p[q], a0);
                    a1 = dot2f(wv.p[q], x1.p[q], a1);
                }
            }
            float* pp = part + (kh * 16 + cp) * 32;
            pp[bp] = a0; pp[bp + 16] = a1;
        }
        __syncthreads();
        // assembly: gate[c][b] = part0 + part1 + eg
        gbufS[ac * 33 + ab] = part[ac * 32 + ab] + part[(16 + ac) * 32 + ab] + egpf;
        egpf = eg_next;
        __syncthreads();
        if (tid < 128) {  // activation: b = tid>>2, u = tid&3
            int b = tid >> 2, u = tid & 3;
            float gi = gbufS[u * 33 + b];
            float gf = gbufS[(4 + u) * 33 + b];
            float gg = gbufS[(8 + u) * 33 + b];
            float go = gbufS[(12 + u) * 33 + b];
            float cc = sigf(gf) * cstS[u * 32 + b] + sigf(gi) * tanh_f(gg);
            float hh = sigf(go) * tanh_f(cc);
            cstS[u * 32 + b] = cc;
            f16 h16 = (f16)hh;
            st_wt_b16(h_hist + (size_t)(t + 1) * 16384 + b * 512 + w * 4 + u, h16);
            st_wt_b16(eh + ((size_t)b * 1024 + t) * 512 + w * 4 + u, h16);
        }
        gbar(flags, w, ++bar);
    }

    // -------- stage decoder weight slices into LDS (overwrites hstage) --------
    __syncthreads();
    {
        int r = tid >> 5, seg = tid & 31;
        const float4* s1 = (const float4*)(Wdih + (size_t)(w * 16 + r) * 512) + seg * 2;
        float4 a1 = s1[0], a2 = s1[1];
        const float4* s2 = (const float4*)(Wdhh + (size_t)(w * 16 + r) * 512) + seg * 2;
        float4 b1 = s2[0], b2 = s2[1];
        float4* d1 = (float4*)(W0s + r * 520) + seg * 2;
        float4* d2 = (float4*)(W1s + r * 520) + seg * 2;
        d1[0] = a1; d1[1] = a2;
        d2[0] = b1; d2[1] = b2;
    }
    __syncthreads();

    // ---------------- decoder: 64 steps, 4 barriers each ----------------
    for (int t = 0; t < 64; t++) {
        const f16* hsrc = h_hist + (size_t)(1024 + t) * 16384;   // prev h
        const f16* qsrc = q_hist + (size_t)t * 16384;            // prev ht
        f16* hdst = h_hist + (size_t)(1025 + t) * 16384;         // yt

        // ---- stage A: gates = dg + Wih_h.ht + Whh.h ----
        {
            float dgv = dg[(size_t)(t * 32 + ab) * 2048 + w * 16 + ac];  // prefetch
            const f16* W1r = W0s + cp * 520 + kh * 256;
            const f16* W2r = W1s + cp * 520 + kh * 256;
            const f16* q0 = qsrc + bp * 512 + kh * 256;
            const f16* q1 = qsrc + (bp + 16) * 512 + kh * 256;
            const f16* h0 = hsrc + bp * 512 + kh * 256;
            const f16* h1 = hsrc + (bp + 16) * 512 + kh * 256;
            float a0 = 0.0f, a1 = 0.0f;
#pragma unroll 2
            for (int k = 0; k < 256; k += 8) {
                V8 w1, w2, x0, x1, y0, y1;
                w1.f4 = *(const float4*)(W1r + k);
                w2.f4 = *(const float4*)(W2r + k);
                x0.f4 = *(const float4*)(q0 + k);
                x1.f4 = *(const float4*)(q1 + k);
                y0.f4 = *(const float4*)(h0 + k);
                y1.f4 = *(const float4*)(h1 + k);
#pragma unroll
                for (int q = 0; q < 4; q++) {
                    a0 = dot2f(w1.p[q], x0.p[q], a0);
                    a1 = dot2f(w1.p[q], x1.p[q], a1);
                    a0 = dot2f(w2.p[q], y0.p[q], a0);
                    a1 = dot2f(w2.p[q], y1.p[q], a1);
                }
            }
            float* pp = part + (kh * 16 + cp) * 32;
            pp[bp] = a0; pp[bp + 16] = a1;
            __syncthreads();
            gbufS[ac * 33 + ab] = part[ac * 32 + ab] + part[(16 + ac) * 32 + ab] + dgv;
            __syncthreads();
            if (tid < 128) {
                int b = tid >> 2, u = tid & 3;
                float gi = gbufS[u * 33 + b];
                float gf = gbufS[(4 + u) * 33 + b];
                float gg = gbufS[(8 + u) * 33 + b];
                float go = gbufS[(12 + u) * 33 + b];
                float cc = sigf(gf) * cstS[u * 32 + b] + sigf(gi) * tanh_f(gg);
                float hh = sigf(go) * tanh_f(cc);
                cstS[u * 32 + b] = cc;
                st_wt_b16(hdst + b * 512 + w * 4 + u, (f16)hh);
            }
        }
        gbar(flags, w, ++bar);               // B1: yt visible
        const f16* yv = hdst;

        // ---- stage B: z = tanh(yt @ W_ht2tan.T) slice; pt partial ----
        {
            int kq = tid >> 7, u = (tid >> 5) & 3, b = tid & 31;
            const f16* Tr = T2l + (size_t)(w * 4 + u) * 512 + kq * 128;
            const f16* yb = yv + b * 512 + kq * 128;
            float z = 0.0f;
#pragma unroll 4
            for (int k = 0; k < 128; k += 8) {
                V8 aa, bb;
                aa.f4 = *(const float4*)(Tr + k);
                bb.f4 = *(const float4*)(yb + k);
#pragma unroll
                for (int q = 0; q < 4; q++) z = dot2f(aa.p[q], bb.p[q], z);
            }
            dpart[(u * 32 + b) * 4 + kq] = z;
        }
        __syncthreads();
        if (tid < 128) {
            int u = tid >> 5, b = tid & 31;
            float z = dpart[tid * 4] + dpart[tid * 4 + 1] + dpart[tid * 4 + 2] + dpart[tid * 4 + 3];
            zbS[u * 33 + b] = tanh_f(z);
        }
        __syncthreads();
        if (tid < 32) {   // write-through partial pt (no atomics)
            float pp = zbS[tid] * wpt[w * 4]
                     + zbS[33 + tid] * wpt[w * 4 + 1]
                     + zbS[66 + tid] * wpt[w * 4 + 2]
                     + zbS[99 + tid] * wpt[w * 4 + 3];
            st_wt_f32(&ppart[(size_t)(t * 32 + tid) * 128 + w], pp);
        }
        gbar(flags, w, ++bar);               // B2: pt partials visible

        // ---- stage C: local attention (WG b < 32 owns batch b) ----
        if (w < 32) {
            const int b = w;
            float* redS = dpart;             // reuse [128] floats
            if (tid < 128) redS[tid] = ppart[(size_t)(t * 32 + b) * 128 + tid];
            __syncthreads();
            {
                float sv = 0.0f;
                if (tid < 64) sv = redS[tid] + redS[tid + 64];
#pragma unroll
                for (int off = 32; off > 0; off >>= 1) sv += __shfl_down(sv, off);
                if (tid == 0) ptS[0] = sv;
            }
            __syncthreads();
            float pt = sigf(ptS[0]);
            float center = 1024.0f * pt;
            int ci = (int)floorf(center);
            int left = max(0, ci - 32);
            int right = min(1024, ci + 32);
            int win = right - left;
            int p = tid >> 3, seg = tid & 7;
            if (p < win) {
                const f16* yr = yv + b * 512 + seg * 64;
                const f16* er = eh + ((size_t)b * 1024 + (left + p)) * 512 + seg * 64;
                float s = 0.0f;
#pragma unroll
                for (int k = 0; k < 64; k += 8) {
                    V8 aa, bb;
                    aa.f4 = *(const float4*)(yr + k);
                    bb.f4 = *(const float4*)(er + k);
#pragma unroll
                    for (int q = 0; q < 4; q++) s = dot2f(aa.p[q], bb.p[q], s);
                }
                spart[p * 9 + seg] = s;
            }
            __syncthreads();
            if (tid < 64) {
                float s = -1e30f;
                if (tid < win) {
                    s = 0.0f;
#pragma unroll
                    for (int x = 0; x < 8; x++) s += spart[tid * 9 + x];
                }
                scS[tid] = s;
            }
            __syncthreads();
            float mx = -1e30f;
            for (int q2 = 0; q2 < 64; q2++) mx = fmaxf(mx, scS[q2]);
            float sum = 0.0f;
            for (int q2 = 0; q2 < 64; q2++) sum += __expf(scS[q2] - mx);
            if (tid < 64) {
                float sp = (float)(left + tid) - center;
                float gs = __expf(-(sp * sp) * (1.0f / 512.0f));
                atwS[tid] = (tid < win) ? (__expf(scS[tid] - mx) / sum) * gs : 0.0f;
            }
            __syncthreads();
            {
                int j = tid;   // 0..511
                float a = 0.0f;
                const f16* ebase = eh + ((size_t)b * 1024 + left) * 512 + j;
                for (int q2 = 0; q2 < win; q2++) a += atwS[q2] * (float)ebase[q2 * 512];
                st_wt_b16(ctb + (size_t)t * 16384 + b * 512 + j, (f16)a);
            }
        }
        gbar(flags, w, ++bar);               // B3: ct visible

        // ---- stage D: ht_new = tanh([ct, yt] @ W_ct2ht.T) slice ----
        {
            int idx = tid >> 2, q4 = tid & 3;   // idx = b*4+u
            int b = idx >> 2, u = idx & 3;
            const f16* Cr = CT2l + (size_t)(w * 4 + u) * 1024 + q4 * 256;
            const f16* xr = (q4 < 2)
                ? (ctb + (size_t)t * 16384 + b * 512 + q4 * 256)
                : (yv + b * 512 + (q4 - 2) * 256);
            float s = 0.0f;
#pragma unroll 4
            for (int k = 0; k < 256; k += 8) {
                V8 aa, bb;
                aa.f4 = *(const float4*)(Cr + k);
                bb.f4 = *(const float4*)(xr + k);
#pragma unroll
                for (int q = 0; q < 4; q++) s = dot2f(aa.p[q], bb.p[q], s);
            }
            dpart[idx * 4 + q4] = s;
        }
        __syncthreads();
        if (tid < 128) {
            int b = tid >> 2, u = tid & 3;
            float hv = tanh_f(dpart[tid * 4] + dpart[tid * 4 + 1] +
                              dpart[tid * 4 + 2] + dpart[tid * 4 + 3]);
            st_wt_b16(q_hist + (size_t)(t + 1) * 16384 + b * 512 + w * 4 + u, (f16)hv);
            dout[(size_t)(t * 32 + b) * 512 + w * 4 + u] = hv;  // cached: next kernel
        }
        gbar(flags, w, ++bar);               // B4: ht ring ready
    }
}

// ---------------------------------------------------------------------------
// Projection + fused exp-sum / target-logit extraction.
// ---------------------------------------------------------------------------
__global__ __launch_bounds__(256) void proj_lse(
    const float* __restrict__ A,      // dec_out [2048][512]
    const float* __restrict__ W,      // [32000][512]
    const int* __restrict__ target,   // [65][32]
    float* __restrict__ se, float* __restrict__ tl) {
    __shared__ float As[16][65];
    __shared__ float Bs[16][65];
    __shared__ float eb[64][17];
    const int tid = threadIdx.x;
    const int v0 = blockIdx.x * 64;
    const int r0 = blockIdx.y * 64;
    const int tx = tid & 15, ty = tid >> 4;
    const int lk = tid & 3,  lr = tid >> 2;
    const float* arow = A + (size_t)(r0 + lr) * 512 + lk * 4;
    const float* brow = W + (size_t)(v0 + lr) * 512 + lk * 4;
    float acc[4][4] = {};
    for (int k0 = 0; k0 < 512; k0 += 16) {
        float4 av = *(const float4*)(arow + k0);
        float4 bv = *(const float4*)(brow + k0);
        __syncthreads();
        As[lk * 4 + 0][lr] = av.x; As[lk * 4 + 1][lr] = av.y;
        As[lk * 4 + 2][lr] = av.z; As[lk * 4 + 3][lr] = av.w;
        Bs[lk * 4 + 0][lr] = bv.x; Bs[lk * 4 + 1][lr] = bv.y;
        Bs[lk * 4 + 2][lr] = bv.z; Bs[lk * 4 + 3][lr] = bv.w;
        __syncthreads();
#pragma unroll
        for (int k = 0; k < 16; k++) {
            float a4[4], b4[4];
#pragma unroll
            for (int i = 0; i < 4; i++) a4[i] = As[k][ty * 4 + i];
#pragma unroll
            for (int j = 0; j < 4; j++) b4[j] = Bs[k][tx * 4 + j];
#pragma unroll
            for (int i = 0; i < 4; i++)
#pragma unroll
                for (int j = 0; j < 4; j++) acc[i][j] = fmaf(a4[i], b4[j], acc[i][j]);
        }
    }
#pragma unroll
    for (int i = 0; i < 4; i++) {
        int rg = r0 + ty * 4 + i;
        int tg = target[32 + rg];
        float es = 0.0f;
#pragma unroll
        for (int j = 0; j < 4; j++) {
            int n = v0 + tx * 4 + j;
            float l = acc[i][j];
            if (n == tg) atomicAdd(&tl[rg], l);
            es += __expf(l);
        }
        eb[ty * 4 + i][tx] = es;
    }
    __syncthreads();
    if (tid < 64) {
        float s = 0.0f;
#pragma unroll
        for (int x = 0; x < 16; x++) s += eb[tid][x];
        atomicAdd(&se[r0 + tid], s);
    }
}

__global__ void finalize_out(const float* __restrict__ se, const float* __restrict__ tl,
                             const int* __restrict__ target, float* __restrict__ out) {
    int b = threadIdx.x;
    if (b >= 32) return;
    float s = 0.0f;
    for (int t = 0; t < 64; t++) {
        int r = t * 32 + b;
        int tg = target[(t + 1) * 32 + b];
        if (tg != 0) s += tl[r] - logf(se[r]);
    }
    out[b] = s;
}

// ---------------------------------------------------------------------------
extern "C" void kernel_launch(void* const* d_in, const int* in_sizes, int n_in,
                              void* d_out, int out_size, void* d_ws, size_t ws_size,
                              hipStream_t stream) {
    const int*   source   = (const int*)  d_in[0];
    const int*   target   = (const int*)  d_in[1];
    const float* src_emb  = (const float*)d_in[2];
    const float* tar_emb  = (const float*)d_in[3];
    const float* enc_Wih  = (const float*)d_in[4];
    const float* enc_Whh  = (const float*)d_in[5];
    const float* enc_b    = (const float*)d_in[6];
    const float* dec_Wih  = (const float*)d_in[7];
    const float* dec_Whh  = (const float*)d_in[8];
    const float* dec_b    = (const float*)d_in[9];
    const float* W_ht2tan = (const float*)d_in[10];
    const float* W_tan2pt = (const float*)d_in[11];
    const float* W_ct2ht  = (const float*)d_in[12];
    const float* W_final  = (const float*)d_in[13];
    float* out = (float*)d_out;

    char* ws = (char*)d_ws;
    size_t off = 0;
    auto alloc = [&](size_t bytes) -> char* {
        char* p = ws + off;
        off = (off + bytes + 255) & ~(size_t)255;
        return p;
    };
    f16*   h_hist = (f16*)  alloc((size_t)1089 * 16384 * 2);   // 34.9 MB
    f16*   q_hist = (f16*)  alloc((size_t)65 * 16384 * 2);
    f16*   ctb    = (f16*)  alloc((size_t)64 * 16384 * 2);
    float* ppart  = (float*)alloc((size_t)64 * 32 * 128 * 4);  // 1 MB
    float* se     = (float*)alloc((size_t)2048 * 4);
    float* tl     = (float*)alloc((size_t)2048 * 4);
    int*   flags  = (int*)  alloc((size_t)NWG * FLAG_STRIDE * 4);
    f16*   eg     = (f16*)  alloc((size_t)32768 * 2048 * 2);
    float* dg     = (float*)alloc((size_t)2048 * 2048 * 4);
    f16*   eh     = (f16*)  alloc((size_t)32 * 1024 * 512 * 2);
    f16*   Wenc   = (f16*)  alloc((size_t)2048 * 512 * 2);
    f16*   Wdih   = (f16*)  alloc((size_t)2048 * 512 * 2);
    f16*   Wdhh   = (f16*)  alloc((size_t)2048 * 512 * 2);
    f16*   T2l    = (f16*)  alloc((size_t)512 * 512 * 2);
    f16*   CT2l   = (f16*)  alloc((size_t)512 * 1024 * 2);
    float* dout   = (float*)alloc((size_t)2048 * 512 * 4);

    zero_init<<<64, 256, 0, stream>>>(h_hist, q_hist, flags, se, tl);
    convert_weights<<<2048, 256, 0, stream>>>(enc_Whh, dec_Wih, dec_Whh, W_ht2tan, W_ct2ht,
                                              Wenc, Wdih, Wdhh, T2l, CT2l);
    gemm_gather<f16><<<dim3(32, 512), 256, 0, stream>>>(src_emb, source, enc_Wih, 512,
                                                        enc_b, eg);
    gemm_gather<float><<<dim3(32, 32), 256, 0, stream>>>(tar_emb, target, dec_Wih, 1024,
                                                         dec_b, dg);
    scan_kernel<<<NWG, 512, 0, stream>>>(eg, dg, Wenc, Wdih, Wdhh, T2l, CT2l, W_tan2pt,
                                         eh, h_hist, q_hist, ctb, ppart, dout, flags);
    proj_lse<<<dim3(500, 32), 256, 0, stream>>>(dout, W_final, target, se, tl);
    finalize_out<<<1, 64, 0, stream>>>(se, tl, target, out);
}

// Round 4
// 9533.372 us; speedup vs baseline: 5.5814x; 1.3111x over previous
//
#include <hip/hip_runtime.h>
#include <stdint.h>
#include <math.h>

// ---------------------------------------------------------------------------
// NMT seq2seq: encoder LSTM (S=1024) -> decoder LSTM + local attention (T=64)
// -> fused projection/log-softmax NLL.
//
// Round 4: (a) hierarchical epoch barrier -- workers publish per-WG flags,
// chain master polls them (1 lane/flag), publishes ONE epoch word, workers
// poll only the epoch (1 lane, 1 line).  Kills the 16K-transaction MALL
// fan-in of round 3's all-poll-all barrier.  (b) 4 independent batch-chains
// (8 batches each) x 64 WGs -- batches are independent recurrences, so the
// sync domain shrinks to 64 WGs and chains overlap each other's stalls.
// eg/dg laid out [t][chain][wg][col][batch] for coalesced staging; eh dropped
// (attention reads h_hist directly).
// ---------------------------------------------------------------------------

typedef _Float16 f16;
typedef _Float16 f16x2 __attribute__((ext_vector_type(2)));

union V8 { f16x2 p[4]; float4 f4; };

#define CH  4            // independent batch chains
#define WPC 64           // workgroups per chain
#define FLAG_STRIDE 32   // ints; 128B per flag line

__device__ __forceinline__ float dot2f(f16x2 a, f16x2 b, float c) {
#if __has_builtin(__builtin_amdgcn_fdot2)
    return __builtin_amdgcn_fdot2(a, b, c, false);
#else
    return c + (float)a[0] * (float)b[0] + (float)a[1] * (float)b[1];
#endif
}

__device__ __forceinline__ float sigf(float x) { return 1.0f / (1.0f + __expf(-x)); }

__device__ __forceinline__ float tanh_f(float x) {
    float ax = fminf(fabsf(x), 12.0f);
    float e  = __expf(2.0f * ax);
    float r  = (e - 1.0f) / (e + 1.0f);
    return copysignf(r, x);
}

// write-through stores: bypass L1/L2, land at coherence point (MALL)
__device__ __forceinline__ void st_wt_b16(f16* p, f16 v) {
    union { f16 h; uint16_t u; } cv; cv.h = v;
    uint32_t d = cv.u;
    asm volatile("global_store_short %0, %1, off sc0 sc1" :: "v"(p), "v"(d) : "memory");
}
__device__ __forceinline__ void st_wt_b32(int* p, int v) {
    asm volatile("global_store_dword %0, %1, off sc0 sc1" :: "v"(p), "v"(v) : "memory");
}
__device__ __forceinline__ void st_wt_f32(float* p, float v) {
    union { float f; int i; } cv; cv.f = v;
    asm volatile("global_store_dword %0, %1, off sc0 sc1" :: "v"(p), "v"(cv.i) : "memory");
}
__device__ __forceinline__ int ld_bypass(const int* p) {
    int v;
    asm volatile("global_load_dword %0, %1, off sc0 sc1\n\ts_waitcnt vmcnt(0)"
                 : "=v"(v) : "v"(p) : "memory");
    return v;
}

// Hierarchical fence-free barrier among the WPC co-resident WGs of one chain.
// flags[0] doubles as the epoch word (master's own flag is implicit).
__device__ __forceinline__ void gbar(int* flags, int wg, int step) {
    asm volatile("s_waitcnt vmcnt(0)" ::: "memory");
    __syncthreads();
    const int tid = threadIdx.x;
    if (wg == 0) {
        if (tid > 0 && tid < WPC) {         // lane w polls flag of WG w
            const int* fp = flags + tid * FLAG_STRIDE;
            while (ld_bypass(fp) < step) __builtin_amdgcn_s_sleep(1);
        }
        if (tid == 0) st_wt_b32(flags, step);   // publish epoch
    } else {
        if (tid == 0) {
            st_wt_b32(flags + wg * FLAG_STRIDE, step);
            while (ld_bypass(flags) < step) __builtin_amdgcn_s_sleep(1);
        }
    }
    __syncthreads();
}

// gate-column permutation: global permuted col n (0..2047) -> original (4H) row.
// n = wg*32 + g*8 + uu  ->  g*512 + wg*8 + uu   (WG wg owns h-units wg*8..wg*8+8)
__device__ __forceinline__ int rowp(int n) {
    return (((n & 31) >> 3) * 512) + ((n >> 5) * 8) + (n & 7);
}

// ---------------------------------------------------------------------------
__global__ void zero_init(f16* h_hist, f16* q_hist, int* flags,
                          float* se, float* tl) {
    int i = blockIdx.x * blockDim.x + threadIdx.x;   // 16384 threads
    if (i < 16384) {
        int chain = i >> 12, off = i & 4095;
        h_hist[(size_t)chain * 1089 * 4096 + off] = (f16)0.0f;
        q_hist[(size_t)chain * 65 * 4096 + off]   = (f16)0.0f;
    }
    if (i < CH * WPC * FLAG_STRIDE) flags[i] = 0;
    if (i < 2048) { se[i] = 0.0f; tl[i] = 0.0f; }
}

// Convert / permute weights to f16 scan layouts.
__global__ void convert_weights(const float* __restrict__ encWhh,
                                const float* __restrict__ decWih,
                                const float* __restrict__ decWhh,
                                const float* __restrict__ ht2tan,
                                const float* __restrict__ ct2ht,
                                f16* __restrict__ Wenc, f16* __restrict__ Wdih,
                                f16* __restrict__ Wdhh, f16* __restrict__ T2l,
                                f16* __restrict__ CT2l) {
    const int NW = 2048 * 512;
    const int total = 3 * NW + 512 * 512 + 512 * 1024;
    int i = blockIdx.x * blockDim.x + threadIdx.x;
    int st = gridDim.x * blockDim.x;
    for (; i < total; i += st) {
        if (i < NW) {
            int n = i >> 9, k = i & 511;
            Wenc[i] = (f16)encWhh[rowp(n) * 512 + k];
        } else if (i < 2 * NW) {
            int j = i - NW; int n = j >> 9, k = j & 511;
            Wdih[j] = (f16)decWih[rowp(n) * 1024 + 512 + k];   // ht part of concat
        } else if (i < 3 * NW) {
            int j = i - 2 * NW; int n = j >> 9, k = j & 511;
            Wdhh[j] = (f16)decWhh[rowp(n) * 512 + k];
        } else if (i < 3 * NW + 512 * 512) {
            int j = i - 3 * NW;
            T2l[j] = (f16)ht2tan[j];
        } else {
            int j = i - 3 * NW - 512 * 512;
            CT2l[j] = (f16)ct2ht[j];
        }
    }
}

// 64x64-tile f32 GEMM, gathered A rows, bias, scan-layout output:
// value for (row r = t*32+B, permuted col n) stored at
// [t][chain=B>>3][wg=n>>5][c=n&31][bb=B&7].
template <typename OutT>
__global__ __launch_bounds__(256) void gemm_gather(
    const float* __restrict__ emb, const int* __restrict__ idx,
    const float* __restrict__ W, int ldw,
    const float* __restrict__ bias, OutT* __restrict__ out) {
    __shared__ float As[16][65];
    __shared__ float Bs[16][65];
    const int tid = threadIdx.x;
    const int n0 = blockIdx.x * 64;
    const int r0 = blockIdx.y * 64;
    const int tx = tid & 15, ty = tid >> 4;
    const int lk = tid & 3,  lr = tid >> 2;
    const float* arow = emb + (size_t)idx[r0 + lr] * 512 + lk * 4;
    const float* brow = W + (size_t)rowp(n0 + lr) * ldw + lk * 4;
    float acc[4][4] = {};
    for (int k0 = 0; k0 < 512; k0 += 16) {
        float4 av = *(const float4*)(arow + k0);
        float4 bv = *(const float4*)(brow + k0);
        __syncthreads();
        As[lk * 4 + 0][lr] = av.x; As[lk * 4 + 1][lr] = av.y;
        As[lk * 4 + 2][lr] = av.z; As[lk * 4 + 3][lr] = av.w;
        Bs[lk * 4 + 0][lr] = bv.x; Bs[lk * 4 + 1][lr] = bv.y;
        Bs[lk * 4 + 2][lr] = bv.z; Bs[lk * 4 + 3][lr] = bv.w;
        __syncthreads();
#pragma unroll
        for (int k = 0; k < 16; k++) {
            float a4[4], b4[4];
#pragma unroll
            for (int i = 0; i < 4; i++) a4[i] = As[k][ty * 4 + i];
#pragma unroll
            for (int j = 0; j < 4; j++) b4[j] = Bs[k][tx * 4 + j];
#pragma unroll
            for (int i = 0; i < 4; i++)
#pragma unroll
                for (int j = 0; j < 4; j++) acc[i][j] = fmaf(a4[i], b4[j], acc[i][j]);
        }
    }
#pragma unroll
    for (int j = 0; j < 4; j++) {
        int n = n0 + tx * 4 + j;
        float bv2 = bias[rowp(n)];
#pragma unroll
        for (int i = 0; i < 4; i++) {
            int r = r0 + ty * 4 + i;
            int t = r >> 5, B = r & 31;
            size_t addr = ((((size_t)t * 4 + (B >> 3)) * 64 + (n >> 5)) * 32
                           + (n & 31)) * 8 + (B & 7);
            out[addr] = (OutT)(acc[i][j] + bv2);
        }
    }
}

// ---------------------------------------------------------------------------
// Persistent scan: 256 WGs x 512 threads = 4 chains x 64 WGs.
// WG (chain, wg) owns 32 permuted gate cols (8 h-units x 4 gates) for the
// chain's 8 batches.
// ---------------------------------------------------------------------------
__global__ __launch_bounds__(512) void scan_kernel(
    const f16* __restrict__ eg,      // [1024][CH][64][32][8]
    const float* __restrict__ dg,    // [64][CH][64][32][8]
    const f16* __restrict__ Wenc,    // [2048][512] rows in permuted col order
    const f16* __restrict__ Wdih,    // [2048][512]
    const f16* __restrict__ Wdhh,    // [2048][512]
    const f16* __restrict__ T2l,     // [512][512]
    const f16* __restrict__ CT2l,    // [512][1024]
    const float* __restrict__ wpt,   // [512]
    f16* __restrict__ h_hist,        // [CH][1089][8][512] slot0 zeroed
    f16* __restrict__ q_hist,        // [CH][65][8][512]  slot0 zeroed
    f16* __restrict__ ctb,           // [64][CH][8][512]
    float* __restrict__ ppart,       // [64][CH][8][64]
    float* __restrict__ dout,        // [2048][512]
    int* flags) {                    // [CH][64*FLAG_STRIDE]
    const int bid = blockIdx.x;
    const int chain = bid >> 6;
    const int wg = bid & 63;
    const int tid = threadIdx.x;
    int bar = 0;

    f16* hc = h_hist + (size_t)chain * 1089 * 4096;
    f16* qc = q_hist + (size_t)chain * 65 * 4096;
    int* flc = flags + chain * WPC * FLAG_STRIDE;

    __shared__ __align__(16) f16  Ws[32 * 520];    // 33280 B
    __shared__ __align__(16) f16  hst[8 * 520];    //  8320 B
    __shared__ float part[512];                    //  2048 B
    __shared__ float zbS[64];
    __shared__ float spart[64 * 9];
    __shared__ float scS[64];
    __shared__ float atwS[64];
    __shared__ float ptS[1];

    // stage encoder weight slice (32 rows x 512) into LDS, 520-f16 padded rows
    {
        int r = tid >> 4, seg = tid & 15;
        const float4* s4 = (const float4*)(Wenc + (size_t)(wg * 32 + r) * 512) + seg * 4;
        float4 a0 = s4[0], a1 = s4[1], a2 = s4[2], a3 = s4[3];
        float4* d4 = (float4*)(Ws + r * 520) + seg * 4;
        d4[0] = a0; d4[1] = a1; d4[2] = a2; d4[3] = a3;
    }
    __syncthreads();

    const int c  = (tid >> 3) & 31;   // gate col (local)
    const int bq = tid & 7;           // batch (local)
    const int kh = tid >> 8;          // k half
    const int sb = tid >> 6, sj = tid & 63;   // h staging
    const int au = tid & 7, ab = tid >> 3;    // activation: uu, bq (tid<64)
    float creg = 0.0f;                // cell state (tid<64)

    float egv = 0.0f;
    if (kh == 0)
        egv = (float)eg[(size_t)chain * 16384 + wg * 256 + c * 8 + bq];

    // ---------------- encoder: 1024 steps, 1 barrier each ----------------
    for (int t = 0; t < 1024; t++) {
        {   // stage h[t] (8KB) -> LDS
            const float4* s4 = (const float4*)(hc + (size_t)t * 4096 + sb * 512) + sj;
            float4 v = *s4;
            *((float4*)(hst + sb * 520) + sj) = v;
        }
        float egn = 0.0f;
        if (kh == 0 && t < 1023)   // prefetch next step's gate (in flight thru dot)
            egn = (float)eg[((size_t)(t + 1) * 4 + chain) * 16384 + wg * 256 + c * 8 + bq];
        __syncthreads();
        {   // dot: col c, batch bq, k-half kh
            const f16* Wr = Ws + c * 520 + kh * 256;
            const f16* hr = hst + bq * 520 + kh * 256;
            float a0 = (kh == 0) ? egv : 0.0f;
#pragma unroll 8
            for (int k = 0; k < 256; k += 8) {
                V8 wv, xv;
                wv.f4 = *(const float4*)(Wr + k);
                xv.f4 = *(const float4*)(hr + k);
#pragma unroll
                for (int q = 0; q < 4; q++) a0 = dot2f(wv.p[q], xv.p[q], a0);
            }
            part[tid] = a0;
        }
        egv = egn;
        __syncthreads();
        if (tid < 64) {
            float gi = part[(au)      * 8 + ab] + part[256 + (au)      * 8 + ab];
            float gf = part[(8 + au)  * 8 + ab] + part[256 + (8 + au)  * 8 + ab];
            float gg = part[(16 + au) * 8 + ab] + part[256 + (16 + au) * 8 + ab];
            float go = part[(24 + au) * 8 + ab] + part[256 + (24 + au) * 8 + ab];
            float cc = sigf(gf) * creg + sigf(gi) * tanh_f(gg);
            float hh = sigf(go) * tanh_f(cc);
            creg = cc;
            st_wt_b16(hc + (size_t)(t + 1) * 4096 + ab * 512 + wg * 8 + au, (f16)hh);
        }
        gbar(flc, wg, ++bar);
    }

    // ---------------- decoder: 64 steps, 4 barriers each ----------------
    for (int t = 0; t < 64; t++) {
        const f16* qsrc = qc + (size_t)t * 4096;          // prev ht
        const f16* hsrc = hc + (size_t)(1024 + t) * 4096; // prev h
        f16* ydst = hc + (size_t)(1025 + t) * 4096;       // yt

        // ---- stage A: gates = dg + Wih_h.ht + Whh.h (weights from L2) ----
        {
            float dgv = (kh == 0)
                ? dg[((size_t)t * 4 + chain) * 16384 + wg * 256 + c * 8 + bq] : 0.0f;
            const f16* W1 = Wdih + (size_t)(wg * 32 + c) * 512 + kh * 256;
            const f16* W2 = Wdhh + (size_t)(wg * 32 + c) * 512 + kh * 256;
            const f16* q0 = qsrc + bq * 512 + kh * 256;
            const f16* h0 = hsrc + bq * 512 + kh * 256;
            float a0 = dgv;
#pragma unroll 4
            for (int k = 0; k < 256; k += 8) {
                V8 w1, w2, x0, y0;
                w1.f4 = *(const float4*)(W1 + k);
                x0.f4 = *(const float4*)(q0 + k);
                w2.f4 = *(const float4*)(W2 + k);
                y0.f4 = *(const float4*)(h0 + k);
#pragma unroll
                for (int q = 0; q < 4; q++) {
                    a0 = dot2f(w1.p[q], x0.p[q], a0);
                    a0 = dot2f(w2.p[q], y0.p[q], a0);
                }
            }
            part[tid] = a0;
        }
        __syncthreads();
        if (tid < 64) {
            float gi = part[(au)      * 8 + ab] + part[256 + (au)      * 8 + ab];
            float gf = part[(8 + au)  * 8 + ab] + part[256 + (8 + au)  * 8 + ab];
            float gg = part[(16 + au) * 8 + ab] + part[256 + (16 + au) * 8 + ab];
            float go = part[(24 + au) * 8 + ab] + part[256 + (24 + au) * 8 + ab];
            float cc = sigf(gf) * creg + sigf(gi) * tanh_f(gg);
            float hh = sigf(go) * tanh_f(cc);
            creg = cc;
            st_wt_b16(ydst + ab * 512 + wg * 8 + au, (f16)hh);
        }
        gbar(flc, wg, ++bar);                 // B1: yt visible

        // ---- stage B: z = tanh(yt @ W_ht2tan.T) units of this WG; pt partial ----
        {
            int kq = tid >> 6, zu = (tid >> 3) & 7, zq = tid & 7;
            const f16* Tr = T2l + (size_t)(wg * 8 + zu) * 512 + kq * 64;
            const f16* yr = ydst + zq * 512 + kq * 64;
            float s = 0.0f;
#pragma unroll
            for (int k = 0; k < 64; k += 8) {
                V8 aa, bb;
                aa.f4 = *(const float4*)(Tr + k);
                bb.f4 = *(const float4*)(yr + k);
#pragma unroll
                for (int q = 0; q < 4; q++) s = dot2f(aa.p[q], bb.p[q], s);
            }
            part[tid] = s;
        }
        __syncthreads();
        if (tid < 64) {
            float z = 0.0f;
#pragma unroll
            for (int kq = 0; kq < 8; kq++) z += part[kq * 64 + tid];
            zbS[tid] = tanh_f(z);             // zbS[zu*8 + zq]
        }
        __syncthreads();
        if (tid < 8) {
            float pp = 0.0f;
#pragma unroll
            for (int u2 = 0; u2 < 8; u2++) pp += zbS[u2 * 8 + tid] * wpt[wg * 8 + u2];
            st_wt_f32(&ppart[(((size_t)t * 4 + chain) * 8 + tid) * 64 + wg], pp);
        }
        gbar(flc, wg, ++bar);                 // B2: pt partials visible

        // ---- stage C: local attention (WG wg<8 owns chain-batch wg) ----
        if (wg < 8) {
            const int bb = wg;
            if (tid < 64) {
                float v = ppart[(((size_t)t * 4 + chain) * 8 + bb) * 64 + tid];
#pragma unroll
                for (int off = 32; off > 0; off >>= 1) v += __shfl_down(v, off);
                if (tid == 0) ptS[0] = v;
            }
            __syncthreads();
            float pt = sigf(ptS[0]);
            float center = 1024.0f * pt;
            int ci = (int)floorf(center);
            int left = max(0, ci - 32);
            int right = min(1024, ci + 32);
            int win = right - left;
            int p = tid >> 3, seg = tid & 7;
            if (p < win) {
                const f16* yr = ydst + bb * 512 + seg * 64;
                const f16* er = hc + (size_t)(left + p + 1) * 4096 + bb * 512 + seg * 64;
                float s = 0.0f;
#pragma unroll
                for (int k = 0; k < 64; k += 8) {
                    V8 aa, bbv;
                    aa.f4  = *(const float4*)(yr + k);
                    bbv.f4 = *(const float4*)(er + k);
#pragma unroll
                    for (int q = 0; q < 4; q++) s = dot2f(aa.p[q], bbv.p[q], s);
                }
                spart[p * 9 + seg] = s;
            }
            __syncthreads();
            if (tid < 64) {
                float s = -1e30f;
                if (tid < win) {
                    s = 0.0f;
#pragma unroll
                    for (int x = 0; x < 8; x++) s += spart[tid * 9 + x];
                }
                scS[tid] = s;
            }
            __syncthreads();
            float mx = -1e30f;
            for (int q2 = 0; q2 < 64; q2++) mx = fmaxf(mx, scS[q2]);
            float sum = 0.0f;
            for (int q2 = 0; q2 < 64; q2++) sum += __expf(scS[q2] - mx);
            if (tid < 64) {
                float sp = (float)(left + tid) - center;
                float gs = __expf(-(sp * sp) * (1.0f / 512.0f));
                atwS[tid] = (tid < win) ? (__expf(scS[tid] - mx) / sum) * gs : 0.0f;
            }
            __syncthreads();
            {
                int j = tid;   // 0..511
                float a = 0.0f;
                const f16* ebase = hc + (size_t)(left + 1) * 4096 + bb * 512 + j;
                for (int p2 = 0; p2 < win; p2++)
                    a += atwS[p2] * (float)ebase[(size_t)p2 * 4096];
                st_wt_b16(ctb + ((((size_t)t * 4 + chain) * 8 + bb) * 512) + j, (f16)a);
            }
        }
        gbar(flc, wg, ++bar);                 // B3: ct visible

        // ---- stage D: ht_new = tanh([ct, yt] @ W_ct2ht.T) units of this WG ----
        {
            int kq = tid >> 6, du = (tid >> 3) & 7, dq = tid & 7;
            const f16* Cr = CT2l + (size_t)(wg * 8 + du) * 1024 + kq * 128;
            const f16* xr = (kq < 4)
                ? (ctb + ((((size_t)t * 4 + chain) * 8 + dq) * 512) + kq * 128)
                : (ydst + dq * 512 + (kq - 4) * 128);
            float s = 0.0f;
#pragma unroll 4
            for (int k = 0; k < 128; k += 8) {
                V8 aa, bb;
                aa.f4 = *(const float4*)(Cr + k);
                bb.f4 = *(const float4*)(xr + k);
#pragma unroll
                for (int q = 0; q < 4; q++) s = dot2f(aa.p[q], bb.p[q], s);
            }
            part[tid] = s;
        }
        __syncthreads();
        if (tid < 64) {
            float s = 0.0f;
#pragma unroll
            for (int kq = 0; kq < 8; kq++) s += part[kq * 64 + tid];
            float hv = tanh_f(s);
            int du = tid >> 3, dq = tid & 7;
            st_wt_b16(qc + (size_t)(t + 1) * 4096 + dq * 512 + wg * 8 + du, (f16)hv);
            dout[((size_t)t * 32 + chain * 8 + dq) * 512 + wg * 8 + du] = hv;
        }
        gbar(flc, wg, ++bar);                 // B4: ht ready
    }
}

// ---------------------------------------------------------------------------
// Projection + fused exp-sum / target-logit extraction.
// ---------------------------------------------------------------------------
__global__ __launch_bounds__(256) void proj_lse(
    const float* __restrict__ A,      // dec_out [2048][512]
    const float* __restrict__ W,      // [32000][512]
    const int* __restrict__ target,   // [65][32]
    float* __restrict__ se, float* __restrict__ tl) {
    __shared__ float As[16][65];
    __shared__ float Bs[16][65];
    __shared__ float eb[64][17];
    const int tid = threadIdx.x;
    const int v0 = blockIdx.x * 64;
    const int r0 = blockIdx.y * 64;
    const int tx = tid & 15, ty = tid >> 4;
    const int lk = tid & 3,  lr = tid >> 2;
    const float* arow = A + (size_t)(r0 + lr) * 512 + lk * 4;
    const float* brow = W + (size_t)(v0 + lr) * 512 + lk * 4;
    float acc[4][4] = {};
    for (int k0 = 0; k0 < 512; k0 += 16) {
        float4 av = *(const float4*)(arow + k0);
        float4 bv = *(const float4*)(brow + k0);
        __syncthreads();
        As[lk * 4 + 0][lr] = av.x; As[lk * 4 + 1][lr] = av.y;
        As[lk * 4 + 2][lr] = av.z; As[lk * 4 + 3][lr] = av.w;
        Bs[lk * 4 + 0][lr] = bv.x; Bs[lk * 4 + 1][lr] = bv.y;
        Bs[lk * 4 + 2][lr] = bv.z; Bs[lk * 4 + 3][lr] = bv.w;
        __syncthreads();
#pragma unroll
        for (int k = 0; k < 16; k++) {
            float a4[4], b4[4];
#pragma unroll
            for (int i = 0; i < 4; i++) a4[i] = As[k][ty * 4 + i];
#pragma unroll
            for (int j = 0; j < 4; j++) b4[j] = Bs[k][tx * 4 + j];
#pragma unroll
            for (int i = 0; i < 4; i++)
#pragma unroll
                for (int j = 0; j < 4; j++) acc[i][j] = fmaf(a4[i], b4[j], acc[i][j]);
        }
    }
#pragma unroll
    for (int i = 0; i < 4; i++) {
        int rg = r0 + ty * 4 + i;
        int tg = target[32 + rg];
        float es = 0.0f;
#pragma unroll
        for (int j = 0; j < 4; j++) {
            int n = v0 + tx * 4 + j;
            float l = acc[i][j];
            if (n == tg) atomicAdd(&tl[rg], l);
            es += __expf(l);
        }
        eb[ty * 4 + i][tx] = es;
    }
    __syncthreads();
    if (tid < 64) {
        float s = 0.0f;
#pragma unroll
        for (int x = 0; x < 16; x++) s += eb[tid][x];
        atomicAdd(&se[r0 + tid], s);
    }
}

__global__ void finalize_out(const float* __restrict__ se, const float* __restrict__ tl,
                             const int* __restrict__ target, float* __restrict__ out) {
    int b = threadIdx.x;
    if (b >= 32) return;
    float s = 0.0f;
    for (int t = 0; t < 64; t++) {
        int r = t * 32 + b;
        int tg = target[(t + 1) * 32 + b];
        if (tg != 0) s += tl[r] - logf(se[r]);
    }
    out[b] = s;
}

// ---------------------------------------------------------------------------
extern "C" void kernel_launch(void* const* d_in, const int* in_sizes, int n_in,
                              void* d_out, int out_size, void* d_ws, size_t ws_size,
                              hipStream_t stream) {
    const int*   source   = (const int*)  d_in[0];
    const int*   target   = (const int*)  d_in[1];
    const float* src_emb  = (const float*)d_in[2];
    const float* tar_emb  = (const float*)d_in[3];
    const float* enc_Wih  = (const float*)d_in[4];
    const float* enc_Whh  = (const float*)d_in[5];
    const float* enc_b    = (const float*)d_in[6];
    const float* dec_Wih  = (const float*)d_in[7];
    const float* dec_Whh  = (const float*)d_in[8];
    const float* dec_b    = (const float*)d_in[9];
    const float* W_ht2tan = (const float*)d_in[10];
    const float* W_tan2pt = (const float*)d_in[11];
    const float* W_ct2ht  = (const float*)d_in[12];
    const float* W_final  = (const float*)d_in[13];
    float* out = (float*)d_out;

    char* ws = (char*)d_ws;
    size_t off = 0;
    auto alloc = [&](size_t bytes) -> char* {
        char* p = ws + off;
        off = (off + bytes + 255) & ~(size_t)255;
        return p;
    };
    f16*   h_hist = (f16*)  alloc((size_t)CH * 1089 * 4096 * 2);  // 35.7 MB
    f16*   q_hist = (f16*)  alloc((size_t)CH * 65 * 4096 * 2);
    f16*   ctb    = (f16*)  alloc((size_t)64 * CH * 8 * 512 * 2);
    float* ppart  = (float*)alloc((size_t)64 * CH * 8 * 64 * 4);
    float* se     = (float*)alloc((size_t)2048 * 4);
    float* tl     = (float*)alloc((size_t)2048 * 4);
    int*   flags  = (int*)  alloc((size_t)CH * WPC * FLAG_STRIDE * 4);
    f16*   eg     = (f16*)  alloc((size_t)32768 * 2048 * 2);      // 128 MB
    float* dg     = (float*)alloc((size_t)2048 * 2048 * 4);       // 16 MB
    f16*   Wenc   = (f16*)  alloc((size_t)2048 * 512 * 2);
    f16*   Wdih   = (f16*)  alloc((size_t)2048 * 512 * 2);
    f16*   Wdhh   = (f16*)  alloc((size_t)2048 * 512 * 2);
    f16*   T2l    = (f16*)  alloc((size_t)512 * 512 * 2);
    f16*   CT2l   = (f16*)  alloc((size_t)512 * 1024 * 2);
    float* dout   = (float*)alloc((size_t)2048 * 512 * 4);

    zero_init<<<64, 256, 0, stream>>>(h_hist, q_hist, flags, se, tl);
    convert_weights<<<2048, 256, 0, stream>>>(enc_Whh, dec_Wih, dec_Whh, W_ht2tan, W_ct2ht,
                                              Wenc, Wdih, Wdhh, T2l, CT2l);
    gemm_gather<f16><<<dim3(32, 512), 256, 0, stream>>>(src_emb, source, enc_Wih, 512,
                                                        enc_b, eg);
    gemm_gather<float><<<dim3(32, 32), 256, 0, stream>>>(tar_emb, target, dec_Wih, 1024,
                                                         dec_b, dg);
    scan_kernel<<<CH * WPC, 512, 0, stream>>>(eg, dg, Wenc, Wdih, Wdhh, T2l, CT2l,
                                              W_tan2pt, h_hist, q_hist, ctb, ppart,
                                              dout, flags);
    proj_lse<<<dim3(500, 32), 256, 0, stream>>>(dout, W_final, target, se, tl);
    finalize_out<<<1, 64, 0, stream>>>(se, tl, target, out);
}